// Round 2
// baseline (547.428 us; speedup 1.0000x reference)
//
#include <hip/hip_runtime.h>

// TranslationIPA: B=1, N=512, CS=384, CZ=128, H=8, C=256, PQ=8, PV=12
// feats layout: [o 2048 | x 96 | y 96 | z 96 | norm 96 | o_pair 256] = 2688

// workspace float offsets
#define OFF_Q      0                         // 512*2048
#define OFF_KV     1048576                   // 512*4096
#define OFF_QPRAW  (OFF_KV + 2097152)        // 512*192
#define OFF_KVPRAW (OFF_QPRAW + 98304)       // 512*480
#define OFF_QPTS   (OFF_KVPRAW + 245760)     // 512*64*3
#define OFF_KVPTS  (OFF_QPTS + 98304)        // 512*160*3
#define OFF_BBIAS  (OFF_KVPTS + 245760)      // 8*512*512 (transposed: [h][i*512+j])
#define OFF_PAIRZ  (OFF_BBIAS + 2097152)     // 512*512*32
#define OFF_ATTN   (OFF_PAIRZ + 8388608)     // 8*512*512
#define OFF_FEATS  (OFF_ATTN + 2097152)      // 512*2688
#define OFF_WCAT   (OFF_FEATS + 1376256)     // 128*40 packed z-weights

// ---------------- generic 64x64 f32 GEMM tile --------------------------------------
__device__ __forceinline__ void sgemm_tile64(
    const float* __restrict__ A, const float* __restrict__ W,
    const float* bias /*nullable*/, float* __restrict__ Cout,
    const int K, const int Ncol, const int row0, const int col0,
    const int k0b, const int k1, const bool atomic,
    float (*As)[64], float (*Bs)[64]) {
  const int t  = threadIdx.x;
  const int tx = t & 15, ty = t >> 4;
  const int am = t >> 2, akq = (t & 3) << 2;
  const int bk = t >> 4, bn = (t & 15) << 2;
  float acc[4][4];
#pragma unroll
  for (int i = 0; i < 4; i++)
#pragma unroll
    for (int j = 0; j < 4; j++) acc[i][j] = 0.f;

  for (int k0 = k0b; k0 < k1; k0 += 16) {
    float4 a4 = *(const float4*)(A + (size_t)(row0 + am) * K + k0 + akq);
    float4 b4;
    {
      const float* wrow = W + (size_t)(k0 + bk) * Ncol;
      int col = col0 + bn;
      if (col + 3 < Ncol) b4 = *(const float4*)(wrow + col);
      else {
        b4.x = (col + 0 < Ncol) ? wrow[col + 0] : 0.f;
        b4.y = (col + 1 < Ncol) ? wrow[col + 1] : 0.f;
        b4.z = (col + 2 < Ncol) ? wrow[col + 2] : 0.f;
        b4.w = (col + 3 < Ncol) ? wrow[col + 3] : 0.f;
      }
    }
    __syncthreads();
    As[akq + 0][am] = a4.x; As[akq + 1][am] = a4.y;
    As[akq + 2][am] = a4.z; As[akq + 3][am] = a4.w;
    *(float4*)&Bs[bk][bn] = b4;
    __syncthreads();
#pragma unroll
    for (int kk = 0; kk < 16; kk++) {
      float4 av = *(const float4*)&As[kk][ty << 2];
      float4 bv = *(const float4*)&Bs[kk][tx << 2];
      acc[0][0] += av.x * bv.x; acc[0][1] += av.x * bv.y; acc[0][2] += av.x * bv.z; acc[0][3] += av.x * bv.w;
      acc[1][0] += av.y * bv.x; acc[1][1] += av.y * bv.y; acc[1][2] += av.y * bv.z; acc[1][3] += av.y * bv.w;
      acc[2][0] += av.z * bv.x; acc[2][1] += av.z * bv.y; acc[2][2] += av.z * bv.z; acc[2][3] += av.z * bv.w;
      acc[3][0] += av.w * bv.x; acc[3][1] += av.w * bv.y; acc[3][2] += av.w * bv.z; acc[3][3] += av.w * bv.w;
    }
  }
#pragma unroll
  for (int i = 0; i < 4; i++) {
    int row = row0 + (ty << 2) + i;
#pragma unroll
    for (int j = 0; j < 4; j++) {
      int col = col0 + (tx << 2) + j;
      if (col < Ncol) {
        float v = acc[i][j] + (bias ? bias[col] : 0.f);
        if (atomic) atomicAdd(&Cout[(size_t)row * Ncol + col], v);
        else Cout[(size_t)row * Ncol + col] = v;
      }
    }
  }
}

// ---------------- fused projections: s @ {wq,wkv,wqp,wkvp} --------------------------
__global__ __launch_bounds__(256) void proj_kernel(
    const float* __restrict__ s,
    const float* __restrict__ wq,  const float* __restrict__ bq,  float* __restrict__ qb,
    const float* __restrict__ wkv, const float* __restrict__ bkv, float* __restrict__ kvb,
    const float* __restrict__ wqp, const float* __restrict__ bqp, float* __restrict__ qpr,
    const float* __restrict__ wkvp,const float* __restrict__ bkvp,float* __restrict__ kvpr) {
  __shared__ float As[16][64], Bs[16][64];
  int bx = blockIdx.x, row0 = blockIdx.y * 64;
  const float *W, *bias; float* out; int Ncol, col0;
  if (bx < 32)      { W = wq;   bias = bq;   out = qb;   Ncol = 2048; col0 = bx * 64; }
  else if (bx < 96) { W = wkv;  bias = bkv;  out = kvb;  Ncol = 4096; col0 = (bx - 32) * 64; }
  else if (bx < 99) { W = wqp;  bias = bqp;  out = qpr;  Ncol = 192;  col0 = (bx - 96) * 64; }
  else              { W = wkvp; bias = bkvp; out = kvpr; Ncol = 480;  col0 = (bx - 99) * 64; }
  sgemm_tile64(s, W, bias, out, 384, Ncol, row0, col0, 0, 384, false, As, Bs);
}

// ---------------- rigid transform of point projections ------------------------------
__global__ __launch_bounds__(256) void rigid_pts(
    const float* __restrict__ qpraw, const float* __restrict__ kvpraw,
    const float* __restrict__ rot, const float* __restrict__ trans,
    float* __restrict__ qpts, float* __restrict__ kvpts) {
  int gid = blockIdx.x * 256 + threadIdx.x;  // 512*224 total, exact
  int n = gid / 224, r = gid % 224;
  const float* R  = rot + n * 9;
  const float* tr = trans + n * 3;
  float px, py, pz; float* dst;
  if (r < 64) {
    const float* src = qpraw + (size_t)n * 192;
    px = src[r]; py = src[64 + r]; pz = src[128 + r];
    dst = qpts + ((size_t)n * 64 + r) * 3;
  } else {
    int p = r - 64;
    const float* src = kvpraw + (size_t)n * 480;
    px = src[p]; py = src[160 + p]; pz = src[320 + p];
    dst = kvpts + ((size_t)n * 160 + p) * 3;
  }
  dst[0] = R[0] * px + R[1] * py + R[2] * pz + tr[0];
  dst[1] = R[3] * px + R[4] * py + R[5] * pz + tr[1];
  dst[2] = R[6] * px + R[7] * py + R[8] * pz + tr[2];
}

// ---------------- pack z-weights: wcat[k][0..7]=wb*sqrt(1/3), [8..39]=wz ------------
__global__ __launch_bounds__(256) void prep_wcat(
    const float* __restrict__ wb, const float* __restrict__ wz,
    float* __restrict__ wcat) {
  int l = blockIdx.x * 256 + threadIdx.x;  // 5120 total
  if (l < 5120) {
    int k = l / 40, n = l % 40;
    wcat[l] = (n < 8) ? wb[k * 8 + n] * 0.5773502691896258f : wz[k * 32 + (n - 8)];
  }
}

// ---------------- z-pass v2: row/thread, uniform weight loads -----------------------
// bbias_t[h*262144 + r] = sqrt(1/3)*(z[r]@wb[:,h] + bb[h]);  pairz[r*32+d] = z@wz + bz
__global__ __launch_bounds__(256, 6) void zpass2(
    const float* __restrict__ z, const float* __restrict__ wcat,
    const float* __restrict__ bb, const float* __restrict__ bz,
    float* __restrict__ bbias_t, float* __restrict__ pairz) {
  const int r = blockIdx.x * 256 + threadIdx.x;   // 0..262143
  const float* zr = z + (size_t)r * 128;
  float acc[40];
#pragma unroll
  for (int n = 0; n < 40; n++) acc[n] = 0.f;

  auto zfma = [&](int kk, float4 zv) {
    const float zz[4] = {zv.x, zv.y, zv.z, zv.w};
#pragma unroll
    for (int c = 0; c < 4; c++) {
      const float* wr = wcat + (kk * 4 + c) * 40;
#pragma unroll
      for (int g = 0; g < 10; g++) {
        float4 w = *(const float4*)(wr + g * 4);
        acc[g * 4 + 0] += zz[c] * w.x;
        acc[g * 4 + 1] += zz[c] * w.y;
        acc[g * 4 + 2] += zz[c] * w.z;
        acc[g * 4 + 3] += zz[c] * w.w;
      }
    }
  };

  float4 cur = *(const float4*)zr;
#pragma unroll 2
  for (int k4 = 0; k4 < 31; k4++) {
    float4 nxt = *(const float4*)(zr + 4 * (k4 + 1));
    zfma(k4, cur);
    cur = nxt;
  }
  zfma(31, cur);

#pragma unroll
  for (int h = 0; h < 8; h++)
    bbias_t[(size_t)h * 262144 + r] = acc[h] + 0.5773502691896258f * bb[h];
  float* pzr = pairz + (size_t)r * 32;
#pragma unroll
  for (int d4 = 0; d4 < 8; d4++) {
    float4 bz4 = *(const float4*)(bz + d4 * 4);
    float4 o;
    o.x = acc[8 + d4 * 4 + 0] + bz4.x;
    o.y = acc[8 + d4 * 4 + 1] + bz4.y;
    o.z = acc[8 + d4 * 4 + 2] + bz4.z;
    o.w = acc[8 + d4 * 4 + 3] + bz4.w;
    *(float4*)(pzr + d4 * 4) = o;
  }
}

// ---------------- logits v2: 64x64 tile, 4x4 reg tile, transposed LDS frags ----------
__global__ __launch_bounds__(256) void logits2(
    const float* __restrict__ qb, const float* __restrict__ kvb,
    const float* __restrict__ qpts, const float* __restrict__ kvpts,
    const float* __restrict__ bbias_t, const float* __restrict__ mask,
    const float* __restrict__ hwp, float* __restrict__ attn) {
  const int jt = blockIdx.x, it = blockIdx.y, h = blockIdx.z;
  const int i0 = it * 64, j0 = jt * 64;
  __shared__ float qT[32][68], kT[32][68];
  __shared__ float qp[64][25], kp[64][25];
  __shared__ float qp2[64], kp2[64];
  const int t = threadIdx.x, tx = t & 15, ty = t >> 4;

  for (int l = t; l < 64 * 24; l += 256) {
    int r = l / 24, w = l % 24;
    qp[r][w] = qpts[((size_t)(i0 + r) * 64 + h * 8) * 3 + w];
    kp[r][w] = kvpts[((size_t)(j0 + r) * 160 + h * 20) * 3 + w];
  }
  __syncthreads();
  if (t < 64) {
    float s1 = 0.f, s2 = 0.f;
#pragma unroll
    for (int w = 0; w < 24; w++) { s1 += qp[t][w] * qp[t][w]; s2 += kp[t][w] * kp[t][w]; }
    qp2[t] = s1; kp2[t] = s2;
  }

  float acc[4][4];
#pragma unroll
  for (int i = 0; i < 4; i++)
#pragma unroll
    for (int j = 0; j < 4; j++) acc[i][j] = 0.f;

  const int si = t & 63, sc = (t >> 6) * 4;
  for (int kc = 0; kc < 256; kc += 32) {
    __syncthreads();
    const float* qrow = qb  + (size_t)(i0 + si) * 2048 + h * 256 + kc;
    const float* krow = kvb + (size_t)(j0 + si) * 4096 + h * 512 + kc;
    float4 a0 = *(const float4*)(qrow + sc);
    float4 a1 = *(const float4*)(qrow + sc + 16);
    float4 b0 = *(const float4*)(krow + sc);
    float4 b1 = *(const float4*)(krow + sc + 16);
    qT[sc + 0][si]  = a0.x; qT[sc + 1][si]  = a0.y; qT[sc + 2][si]  = a0.z; qT[sc + 3][si]  = a0.w;
    qT[sc + 16][si] = a1.x; qT[sc + 17][si] = a1.y; qT[sc + 18][si] = a1.z; qT[sc + 19][si] = a1.w;
    kT[sc + 0][si]  = b0.x; kT[sc + 1][si]  = b0.y; kT[sc + 2][si]  = b0.z; kT[sc + 3][si]  = b0.w;
    kT[sc + 16][si] = b1.x; kT[sc + 17][si] = b1.y; kT[sc + 18][si] = b1.z; kT[sc + 19][si] = b1.w;
    __syncthreads();
#pragma unroll
    for (int k = 0; k < 32; k++) {
      float4 a4 = *(const float4*)&qT[k][ty << 2];
      float4 b4 = *(const float4*)&kT[k][tx << 2];
      acc[0][0] += a4.x * b4.x; acc[0][1] += a4.x * b4.y; acc[0][2] += a4.x * b4.z; acc[0][3] += a4.x * b4.w;
      acc[1][0] += a4.y * b4.x; acc[1][1] += a4.y * b4.y; acc[1][2] += a4.y * b4.z; acc[1][3] += a4.y * b4.w;
      acc[2][0] += a4.z * b4.x; acc[2][1] += a4.z * b4.y; acc[2][2] += a4.z * b4.z; acc[2][3] += a4.z * b4.w;
      acc[3][0] += a4.w * b4.x; acc[3][1] += a4.w * b4.y; acc[3][2] += a4.w * b4.z; acc[3][3] += a4.w * b4.w;
    }
  }

  const float c1 = 0.03608439182435161f;                    // 1/sqrt(768)
  const float hw = log1pf(expf(hwp[h])) * 0.09622504486493764f;  // softplus * sqrt(1/108)
  float4 mj4 = *(const float4*)(mask + j0 + tx * 4);
  const float mjv[4] = {mj4.x, mj4.y, mj4.z, mj4.w};
#pragma unroll
  for (int ii = 0; ii < 4; ii++) {
    const int i = i0 + (ty << 2) + ii;
    const float mi = mask[i];
    float4 bb4 = *(const float4*)(bbias_t + (size_t)h * 262144 + (size_t)i * 512 + j0 + tx * 4);
    const float bbv[4] = {bb4.x, bb4.y, bb4.z, bb4.w};
    const float qi2 = qp2[(ty << 2) + ii];
    float res[4];
#pragma unroll
    for (int jj = 0; jj < 4; jj++) {
      float cross = 0.f;
#pragma unroll
      for (int w = 0; w < 24; w++) cross += qp[(ty << 2) + ii][w] * kp[(tx << 2) + jj][w];
      float pt = qi2 + kp2[(tx << 2) + jj] - 2.f * cross;
      res[jj] = c1 * acc[ii][jj] + bbv[jj] - 0.5f * hw * pt + 100000.f * (mi * mjv[jj] - 1.f);
    }
    float4 outv = {res[0], res[1], res[2], res[3]};
    *(float4*)(attn + ((size_t)h * 512 + i) * 512 + j0 + tx * 4) = outv;
  }
}

// ---------------- row softmax over j (512), in place --------------------------------
__global__ __launch_bounds__(256) void softmax_kernel(float* __restrict__ attn) {
  float* a = attn + (size_t)blockIdx.x * 512;
  const int t = threadIdx.x;
  float v0 = a[t], v1 = a[t + 256];
  __shared__ float redm[4], reds[4];
  float m = fmaxf(v0, v1);
#pragma unroll
  for (int o = 1; o < 64; o <<= 1) m = fmaxf(m, __shfl_xor(m, o));
  if ((t & 63) == 0) redm[t >> 6] = m;
  __syncthreads();
  m = fmaxf(fmaxf(redm[0], redm[1]), fmaxf(redm[2], redm[3]));
  float e0 = expf(v0 - m), e1 = expf(v1 - m);
  float s = e0 + e1;
#pragma unroll
  for (int o = 1; o < 64; o <<= 1) s += __shfl_xor(s, o);
  if ((t & 63) == 0) reds[t >> 6] = s;
  __syncthreads();
  float inv = 1.0f / (reds[0] + reds[1] + reds[2] + reds[3]);
  a[t] = e0 * inv;
  a[t + 256] = e1 * inv;
}

// ---------------- o = a@v, o_pt = a@v_pts (+inverse rigid, norm) ---------------------
__global__ __launch_bounds__(256) void attn_v2(
    const float* __restrict__ attn, const float* __restrict__ kvb,
    const float* __restrict__ kvpts, const float* __restrict__ rot,
    const float* __restrict__ trans, float* __restrict__ feats) {
  const int it = blockIdx.x, h = blockIdx.y;   // grid (64, 8)
  const int i0 = it * 8;
  __shared__ float as[8][516];
  __shared__ float opt[8][36];
  const int t = threadIdx.x;
  for (int l = t; l < 8 * 128; l += 256) {
    int i = l >> 7, j4 = (l & 127) * 4;
    *(float4*)&as[i][j4] = *(const float4*)(attn + ((size_t)h * 512 + i0 + i) * 512 + j4);
  }
  __syncthreads();
  const int tx = t & 63, wid = t >> 6;
  const int iA = wid * 2;
  const bool do_p = tx < 36;
  const float* vbase = kvb + h * 512 + 256 + tx * 4;
  const float* pbase = kvpts + ((size_t)(h * 20 + 8)) * 3 + tx;
  float acc[2][4];
#pragma unroll
  for (int i = 0; i < 2; i++)
#pragma unroll
    for (int j = 0; j < 4; j++) acc[i][j] = 0.f;
  float accp[2] = {0.f, 0.f};

  for (int j = 0; j < 512; j += 4) {
    float4 aA = *(const float4*)&as[iA][j];
    float4 aB = *(const float4*)&as[iA + 1][j];
    const float fA[4] = {aA.x, aA.y, aA.z, aA.w};
    const float fB[4] = {aB.x, aB.y, aB.z, aB.w};
#pragma unroll
    for (int u = 0; u < 4; u++) {
      float4 v4 = *(const float4*)(vbase + (size_t)(j + u) * 4096);
      float vp = do_p ? pbase[(size_t)(j + u) * 480] : 0.f;
      acc[0][0] += fA[u] * v4.x; acc[0][1] += fA[u] * v4.y;
      acc[0][2] += fA[u] * v4.z; acc[0][3] += fA[u] * v4.w;
      acc[1][0] += fB[u] * v4.x; acc[1][1] += fB[u] * v4.y;
      acc[1][2] += fB[u] * v4.z; acc[1][3] += fB[u] * v4.w;
      accp[0] += fA[u] * vp;
      accp[1] += fB[u] * vp;
    }
  }
#pragma unroll
  for (int ii = 0; ii < 2; ii++) {
    int irow = i0 + iA + ii;
    float4 o4 = {acc[ii][0], acc[ii][1], acc[ii][2], acc[ii][3]};
    *(float4*)(feats + (size_t)irow * 2688 + h * 256 + tx * 4) = o4;
    if (do_p) opt[iA + ii][tx] = accp[ii];
  }
  __syncthreads();
  if (t < 96) {
    int i = t / 12, p = t % 12, irow = i0 + i;
    const float* R = rot + irow * 9;
    const float* tr = trans + irow * 3;
    float x = opt[i][p * 3 + 0] - tr[0];
    float y = opt[i][p * 3 + 1] - tr[1];
    float zz = opt[i][p * 3 + 2] - tr[2];
    float o0 = R[0] * x + R[3] * y + R[6] * zz;   // R^T v
    float o1 = R[1] * x + R[4] * y + R[7] * zz;
    float o2 = R[2] * x + R[5] * y + R[8] * zz;
    float nrm = sqrtf(o0 * o0 + o1 * o1 + o2 * o2 + 1e-8f);
    float* fr = feats + (size_t)irow * 2688 + 2048;
    fr[h * 12 + p]       = o0;
    fr[96 + h * 12 + p]  = o1;
    fr[192 + h * 12 + p] = o2;
    fr[288 + h * 12 + p] = nrm;
  }
}

// ---------------- o_pair = a @ pair_z (per query i) ----------------------------------
__global__ __launch_bounds__(256) void o_pair_kernel(
    const float* __restrict__ attn, const float* __restrict__ pairz,
    float* __restrict__ feats) {
  const int i = blockIdx.x;
  __shared__ float as[8][512];
  __shared__ float pzt[64][33];
  const int t = threadIdx.x;
  for (int l = t; l < 8 * 128; l += 256) {
    int hh = l >> 7, j4 = (l & 127) * 4;
    *(float4*)&as[hh][j4] = *(const float4*)(attn + ((size_t)hh * 512 + i) * 512 + j4);
  }
  const int h = t >> 5, d = t & 31;
  float acc = 0.f;
  for (int jt = 0; jt < 512; jt += 64) {
    __syncthreads();
    for (int l = t; l < 64 * 8; l += 256) {
      int j = l >> 3, d4 = (l & 7) * 4;
      float4 p4 = *(const float4*)(pairz + ((size_t)i * 512 + jt + j) * 32 + d4);
      pzt[j][d4 + 0] = p4.x; pzt[j][d4 + 1] = p4.y;
      pzt[j][d4 + 2] = p4.z; pzt[j][d4 + 3] = p4.w;
    }
    __syncthreads();
#pragma unroll
    for (int j = 0; j < 64; j += 4) {
      float4 a4 = *(const float4*)&as[h][jt + j];
      acc += a4.x * pzt[j][d] + a4.y * pzt[j + 1][d] + a4.z * pzt[j + 2][d] + a4.w * pzt[j + 3][d];
    }
  }
  feats[(size_t)i * 2688 + 2432 + h * 32 + d] = acc;
}

// ---------------- final GEMM: out = feats @ wo + bo (split-K=8, atomic) --------------
__global__ __launch_bounds__(256) void out_gemm_kernel(
    const float* __restrict__ feats, const float* __restrict__ wo,
    const float* __restrict__ bo, float* __restrict__ out) {
  __shared__ float As[16][64], Bs[16][64];
  int col0 = blockIdx.x * 64, row0 = blockIdx.y * 64;
  int k0 = blockIdx.z * 336;
  sgemm_tile64(feats, wo, blockIdx.z == 0 ? bo : nullptr, out,
               2688, 384, row0, col0, k0, k0 + 336, true, As, Bs);
}

extern "C" void kernel_launch(void* const* d_in, const int* in_sizes, int n_in,
                              void* d_out, int out_size, void* d_ws, size_t ws_size,
                              hipStream_t stream) {
  const float* s     = (const float*)d_in[0];
  const float* z     = (const float*)d_in[1];
  const float* rot   = (const float*)d_in[2];
  const float* trans = (const float*)d_in[3];
  const float* mask  = (const float*)d_in[4];
  const float* wq    = (const float*)d_in[5];
  const float* bq    = (const float*)d_in[6];
  const float* wkv   = (const float*)d_in[7];
  const float* bkv   = (const float*)d_in[8];
  const float* wqp   = (const float*)d_in[9];
  const float* bqp   = (const float*)d_in[10];
  const float* wkvp  = (const float*)d_in[11];
  const float* bkvp  = (const float*)d_in[12];
  const float* wb    = (const float*)d_in[13];
  const float* bb    = (const float*)d_in[14];
  const float* wz    = (const float*)d_in[15];
  const float* bz    = (const float*)d_in[16];
  const float* hwp   = (const float*)d_in[17];
  const float* wo    = (const float*)d_in[18];
  const float* bo    = (const float*)d_in[19];
  float* out = (float*)d_out;

  float* ws = (float*)d_ws;
  float* qb      = ws + OFF_Q;
  float* kvb     = ws + OFF_KV;
  float* qpraw   = ws + OFF_QPRAW;
  float* kvpraw  = ws + OFF_KVPRAW;
  float* qpts    = ws + OFF_QPTS;
  float* kvpts   = ws + OFF_KVPTS;
  float* bbias_t = ws + OFF_BBIAS;
  float* pairz   = ws + OFF_PAIRZ;
  float* attn    = ws + OFF_ATTN;
  float* feats   = ws + OFF_FEATS;
  float* wcat    = ws + OFF_WCAT;

  proj_kernel<<<dim3(107, 8), 256, 0, stream>>>(s, wq, bq, qb, wkv, bkv, kvb,
                                                wqp, bqp, qpraw, wkvp, bkvp, kvpraw);
  rigid_pts<<<448, 256, 0, stream>>>(qpraw, kvpraw, rot, trans, qpts, kvpts);
  prep_wcat<<<20, 256, 0, stream>>>(wb, wz, wcat);
  zpass2<<<1024, 256, 0, stream>>>(z, wcat, bb, bz, bbias_t, pairz);
  logits2<<<dim3(8, 8, 8), 256, 0, stream>>>(qb, kvb, qpts, kvpts, bbias_t, mask, hwp, attn);
  softmax_kernel<<<4096, 256, 0, stream>>>(attn);
  attn_v2<<<dim3(64, 8), 256, 0, stream>>>(attn, kvb, kvpts, rot, trans, feats);
  o_pair_kernel<<<512, 256, 0, stream>>>(attn, pairz, feats);
  (void)hipMemsetAsync(out, 0, (size_t)out_size * sizeof(float), stream);
  out_gemm_kernel<<<dim3(6, 8, 8), 256, 0, stream>>>(feats, wo, bo, out);
}

// Round 3
// 494.491 us; speedup vs baseline: 1.1071x; 1.1071x over previous
//
#include <hip/hip_runtime.h>

// TranslationIPA: B=1, N=512, CS=384, CZ=128, H=8, C=256, PQ=8, PV=12
// feats layout: [o 2048 | x 96 | y 96 | z 96 | norm 96 | o_pair 256] = 2688

// workspace float offsets
#define OFF_Q      0                         // 512*2048
#define OFF_KV     1048576                   // 512*4096
#define OFF_QPRAW  (OFF_KV + 2097152)        // 512*192
#define OFF_KVPRAW (OFF_QPRAW + 98304)       // 512*480
#define OFF_QPTS   (OFF_KVPRAW + 245760)     // 512*64*3
#define OFF_KVPTS  (OFF_QPTS + 98304)        // 512*160*3
#define OFF_BBIAS  (OFF_KVPTS + 245760)      // 8*512*512 (transposed: [h][i*512+j])
#define OFF_PAIRZ  (OFF_BBIAS + 2097152)     // 512*512*32
#define OFF_ATTN   (OFF_PAIRZ + 8388608)     // 8*512*512
#define OFF_FEATS  (OFF_ATTN + 2097152)      // 512*2688
#define OFF_WCAT   (OFF_FEATS + 1376256)     // 128*40 packed z-weights

// ---------------- generic 64x64 f32 GEMM tile --------------------------------------
__device__ __forceinline__ void sgemm_tile64(
    const float* __restrict__ A, const float* __restrict__ W,
    const float* bias /*nullable*/, float* __restrict__ Cout,
    const int K, const int Ncol, const int row0, const int col0,
    const int k0b, const int k1, const bool atomic,
    float (*As)[64], float (*Bs)[64]) {
  const int t  = threadIdx.x;
  const int tx = t & 15, ty = t >> 4;
  const int am = t >> 2, akq = (t & 3) << 2;
  const int bk = t >> 4, bn = (t & 15) << 2;
  float acc[4][4];
#pragma unroll
  for (int i = 0; i < 4; i++)
#pragma unroll
    for (int j = 0; j < 4; j++) acc[i][j] = 0.f;

  for (int k0 = k0b; k0 < k1; k0 += 16) {
    float4 a4 = *(const float4*)(A + (size_t)(row0 + am) * K + k0 + akq);
    float4 b4;
    {
      const float* wrow = W + (size_t)(k0 + bk) * Ncol;
      int col = col0 + bn;
      if (col + 3 < Ncol) b4 = *(const float4*)(wrow + col);
      else {
        b4.x = (col + 0 < Ncol) ? wrow[col + 0] : 0.f;
        b4.y = (col + 1 < Ncol) ? wrow[col + 1] : 0.f;
        b4.z = (col + 2 < Ncol) ? wrow[col + 2] : 0.f;
        b4.w = (col + 3 < Ncol) ? wrow[col + 3] : 0.f;
      }
    }
    __syncthreads();
    As[akq + 0][am] = a4.x; As[akq + 1][am] = a4.y;
    As[akq + 2][am] = a4.z; As[akq + 3][am] = a4.w;
    *(float4*)&Bs[bk][bn] = b4;
    __syncthreads();
#pragma unroll
    for (int kk = 0; kk < 16; kk++) {
      float4 av = *(const float4*)&As[kk][ty << 2];
      float4 bv = *(const float4*)&Bs[kk][tx << 2];
      acc[0][0] += av.x * bv.x; acc[0][1] += av.x * bv.y; acc[0][2] += av.x * bv.z; acc[0][3] += av.x * bv.w;
      acc[1][0] += av.y * bv.x; acc[1][1] += av.y * bv.y; acc[1][2] += av.y * bv.z; acc[1][3] += av.y * bv.w;
      acc[2][0] += av.z * bv.x; acc[2][1] += av.z * bv.y; acc[2][2] += av.z * bv.z; acc[2][3] += av.z * bv.w;
      acc[3][0] += av.w * bv.x; acc[3][1] += av.w * bv.y; acc[3][2] += av.w * bv.z; acc[3][3] += av.w * bv.w;
    }
  }
#pragma unroll
  for (int i = 0; i < 4; i++) {
    int row = row0 + (ty << 2) + i;
#pragma unroll
    for (int j = 0; j < 4; j++) {
      int col = col0 + (tx << 2) + j;
      if (col < Ncol) {
        float v = acc[i][j] + (bias ? bias[col] : 0.f);
        if (atomic) atomicAdd(&Cout[(size_t)row * Ncol + col], v);
        else Cout[(size_t)row * Ncol + col] = v;
      }
    }
  }
}

// ---------------- fused projections: s @ {wq,wkv,wqp,wkvp} --------------------------
__global__ __launch_bounds__(256) void proj_kernel(
    const float* __restrict__ s,
    const float* __restrict__ wq,  const float* __restrict__ bq,  float* __restrict__ qb,
    const float* __restrict__ wkv, const float* __restrict__ bkv, float* __restrict__ kvb,
    const float* __restrict__ wqp, const float* __restrict__ bqp, float* __restrict__ qpr,
    const float* __restrict__ wkvp,const float* __restrict__ bkvp,float* __restrict__ kvpr) {
  __shared__ float As[16][64], Bs[16][64];
  int bx = blockIdx.x, row0 = blockIdx.y * 64;
  const float *W, *bias; float* out; int Ncol, col0;
  if (bx < 32)      { W = wq;   bias = bq;   out = qb;   Ncol = 2048; col0 = bx * 64; }
  else if (bx < 96) { W = wkv;  bias = bkv;  out = kvb;  Ncol = 4096; col0 = (bx - 32) * 64; }
  else if (bx < 99) { W = wqp;  bias = bqp;  out = qpr;  Ncol = 192;  col0 = (bx - 96) * 64; }
  else              { W = wkvp; bias = bkvp; out = kvpr; Ncol = 480;  col0 = (bx - 99) * 64; }
  sgemm_tile64(s, W, bias, out, 384, Ncol, row0, col0, 0, 384, false, As, Bs);
}

// ---------------- rigid transform of point projections ------------------------------
__global__ __launch_bounds__(256) void rigid_pts(
    const float* __restrict__ qpraw, const float* __restrict__ kvpraw,
    const float* __restrict__ rot, const float* __restrict__ trans,
    float* __restrict__ qpts, float* __restrict__ kvpts) {
  int gid = blockIdx.x * 256 + threadIdx.x;  // 512*224 total, exact
  int n = gid / 224, r = gid % 224;
  const float* R  = rot + n * 9;
  const float* tr = trans + n * 3;
  float px, py, pz; float* dst;
  if (r < 64) {
    const float* src = qpraw + (size_t)n * 192;
    px = src[r]; py = src[64 + r]; pz = src[128 + r];
    dst = qpts + ((size_t)n * 64 + r) * 3;
  } else {
    int p = r - 64;
    const float* src = kvpraw + (size_t)n * 480;
    px = src[p]; py = src[160 + p]; pz = src[320 + p];
    dst = kvpts + ((size_t)n * 160 + p) * 3;
  }
  dst[0] = R[0] * px + R[1] * py + R[2] * pz + tr[0];
  dst[1] = R[3] * px + R[4] * py + R[5] * pz + tr[1];
  dst[2] = R[6] * px + R[7] * py + R[8] * pz + tr[2];
}

// ---------------- pack z-weights: wcat[k][0..7]=wb*sqrt(1/3), [8..39]=wz ------------
__global__ __launch_bounds__(256) void prep_wcat(
    const float* __restrict__ wb, const float* __restrict__ wz,
    float* __restrict__ wcat) {
  int l = blockIdx.x * 256 + threadIdx.x;  // 5120 total
  if (l < 5120) {
    int k = l / 40, n = l % 40;
    wcat[l] = (n < 8) ? wb[k * 8 + n] * 0.5773502691896258f : wz[k * 32 + (n - 8)];
  }
}

// ---------------- z-pass v3: row/thread, uniform weight loads, NO reg cap -----------
// bbias_t[h*262144 + r] = sqrt(1/3)*(z[r]@wb[:,h] + bb[h]);  pairz[r*32+d] = z@wz + bz
__global__ __launch_bounds__(256) void zpass2(
    const float* __restrict__ z, const float* __restrict__ wcat,
    const float* __restrict__ bb, const float* __restrict__ bz,
    float* __restrict__ bbias_t, float* __restrict__ pairz) {
  const int r = blockIdx.x * 256 + threadIdx.x;   // 0..262143
  const float* zr = z + (size_t)r * 128;
  float acc[40];
#pragma unroll
  for (int n = 0; n < 40; n++) acc[n] = 0.f;

  auto zfma = [&](int kk, float4 zv) {
    const float zz[4] = {zv.x, zv.y, zv.z, zv.w};
#pragma unroll
    for (int c = 0; c < 4; c++) {
      const float* wr = wcat + (kk * 4 + c) * 40;
#pragma unroll
      for (int g = 0; g < 10; g++) {
        float4 w = *(const float4*)(wr + g * 4);
        acc[g * 4 + 0] += zz[c] * w.x;
        acc[g * 4 + 1] += zz[c] * w.y;
        acc[g * 4 + 2] += zz[c] * w.z;
        acc[g * 4 + 3] += zz[c] * w.w;
      }
    }
  };

  float4 cur = *(const float4*)zr;
#pragma unroll 2
  for (int k4 = 0; k4 < 31; k4++) {
    float4 nxt = *(const float4*)(zr + 4 * (k4 + 1));
    zfma(k4, cur);
    cur = nxt;
  }
  zfma(31, cur);

#pragma unroll
  for (int h = 0; h < 8; h++)
    bbias_t[(size_t)h * 262144 + r] = acc[h] + 0.5773502691896258f * bb[h];
  float* pzr = pairz + (size_t)r * 32;
#pragma unroll
  for (int d4 = 0; d4 < 8; d4++) {
    float4 bz4 = *(const float4*)(bz + d4 * 4);
    float4 o;
    o.x = acc[8 + d4 * 4 + 0] + bz4.x;
    o.y = acc[8 + d4 * 4 + 1] + bz4.y;
    o.z = acc[8 + d4 * 4 + 2] + bz4.z;
    o.w = acc[8 + d4 * 4 + 3] + bz4.w;
    *(float4*)(pzr + d4 * 4) = o;
  }
}

// ---------------- logits v2: 64x64 tile, 4x4 reg tile, transposed LDS frags ----------
__global__ __launch_bounds__(256) void logits2(
    const float* __restrict__ qb, const float* __restrict__ kvb,
    const float* __restrict__ qpts, const float* __restrict__ kvpts,
    const float* __restrict__ bbias_t, const float* __restrict__ mask,
    const float* __restrict__ hwp, float* __restrict__ attn) {
  const int jt = blockIdx.x, it = blockIdx.y, h = blockIdx.z;
  const int i0 = it * 64, j0 = jt * 64;
  __shared__ float qT[32][68], kT[32][68];
  __shared__ float qp[64][25], kp[64][25];
  __shared__ float qp2[64], kp2[64];
  const int t = threadIdx.x, tx = t & 15, ty = t >> 4;

  for (int l = t; l < 64 * 24; l += 256) {
    int r = l / 24, w = l % 24;
    qp[r][w] = qpts[((size_t)(i0 + r) * 64 + h * 8) * 3 + w];
    kp[r][w] = kvpts[((size_t)(j0 + r) * 160 + h * 20) * 3 + w];
  }
  __syncthreads();
  if (t < 64) {
    float s1 = 0.f, s2 = 0.f;
#pragma unroll
    for (int w = 0; w < 24; w++) { s1 += qp[t][w] * qp[t][w]; s2 += kp[t][w] * kp[t][w]; }
    qp2[t] = s1; kp2[t] = s2;
  }

  float acc[4][4];
#pragma unroll
  for (int i = 0; i < 4; i++)
#pragma unroll
    for (int j = 0; j < 4; j++) acc[i][j] = 0.f;

  const int si = t & 63, sc = (t >> 6) * 4;
  for (int kc = 0; kc < 256; kc += 32) {
    __syncthreads();
    const float* qrow = qb  + (size_t)(i0 + si) * 2048 + h * 256 + kc;
    const float* krow = kvb + (size_t)(j0 + si) * 4096 + h * 512 + kc;
    float4 a0 = *(const float4*)(qrow + sc);
    float4 a1 = *(const float4*)(qrow + sc + 16);
    float4 b0 = *(const float4*)(krow + sc);
    float4 b1 = *(const float4*)(krow + sc + 16);
    qT[sc + 0][si]  = a0.x; qT[sc + 1][si]  = a0.y; qT[sc + 2][si]  = a0.z; qT[sc + 3][si]  = a0.w;
    qT[sc + 16][si] = a1.x; qT[sc + 17][si] = a1.y; qT[sc + 18][si] = a1.z; qT[sc + 19][si] = a1.w;
    kT[sc + 0][si]  = b0.x; kT[sc + 1][si]  = b0.y; kT[sc + 2][si]  = b0.z; kT[sc + 3][si]  = b0.w;
    kT[sc + 16][si] = b1.x; kT[sc + 17][si] = b1.y; kT[sc + 18][si] = b1.z; kT[sc + 19][si] = b1.w;
    __syncthreads();
#pragma unroll
    for (int k = 0; k < 32; k++) {
      float4 a4 = *(const float4*)&qT[k][ty << 2];
      float4 b4 = *(const float4*)&kT[k][tx << 2];
      acc[0][0] += a4.x * b4.x; acc[0][1] += a4.x * b4.y; acc[0][2] += a4.x * b4.z; acc[0][3] += a4.x * b4.w;
      acc[1][0] += a4.y * b4.x; acc[1][1] += a4.y * b4.y; acc[1][2] += a4.y * b4.z; acc[1][3] += a4.y * b4.w;
      acc[2][0] += a4.z * b4.x; acc[2][1] += a4.z * b4.y; acc[2][2] += a4.z * b4.z; acc[2][3] += a4.z * b4.w;
      acc[3][0] += a4.w * b4.x; acc[3][1] += a4.w * b4.y; acc[3][2] += a4.w * b4.z; acc[3][3] += a4.w * b4.w;
    }
  }

  const float c1 = 0.03608439182435161f;                    // 1/sqrt(768)
  const float hw = log1pf(expf(hwp[h])) * 0.09622504486493764f;  // softplus * sqrt(1/108)
  float4 mj4 = *(const float4*)(mask + j0 + tx * 4);
  const float mjv[4] = {mj4.x, mj4.y, mj4.z, mj4.w};
#pragma unroll
  for (int ii = 0; ii < 4; ii++) {
    const int i = i0 + (ty << 2) + ii;
    const float mi = mask[i];
    float4 bb4 = *(const float4*)(bbias_t + (size_t)h * 262144 + (size_t)i * 512 + j0 + tx * 4);
    const float bbv[4] = {bb4.x, bb4.y, bb4.z, bb4.w};
    const float qi2 = qp2[(ty << 2) + ii];
    float res[4];
#pragma unroll
    for (int jj = 0; jj < 4; jj++) {
      float cross = 0.f;
#pragma unroll
      for (int w = 0; w < 24; w++) cross += qp[(ty << 2) + ii][w] * kp[(tx << 2) + jj][w];
      float pt = qi2 + kp2[(tx << 2) + jj] - 2.f * cross;
      res[jj] = c1 * acc[ii][jj] + bbv[jj] - 0.5f * hw * pt + 100000.f * (mi * mjv[jj] - 1.f);
    }
    float4 outv = {res[0], res[1], res[2], res[3]};
    *(float4*)(attn + ((size_t)h * 512 + i) * 512 + j0 + tx * 4) = outv;
  }
}

// ---------------- row softmax over j (512), in place --------------------------------
__global__ __launch_bounds__(256) void softmax_kernel(float* __restrict__ attn) {
  float* a = attn + (size_t)blockIdx.x * 512;
  const int t = threadIdx.x;
  float v0 = a[t], v1 = a[t + 256];
  __shared__ float redm[4], reds[4];
  float m = fmaxf(v0, v1);
#pragma unroll
  for (int o = 1; o < 64; o <<= 1) m = fmaxf(m, __shfl_xor(m, o));
  if ((t & 63) == 0) redm[t >> 6] = m;
  __syncthreads();
  m = fmaxf(fmaxf(redm[0], redm[1]), fmaxf(redm[2], redm[3]));
  float e0 = expf(v0 - m), e1 = expf(v1 - m);
  float s = e0 + e1;
#pragma unroll
  for (int o = 1; o < 64; o <<= 1) s += __shfl_xor(s, o);
  if ((t & 63) == 0) reds[t >> 6] = s;
  __syncthreads();
  float inv = 1.0f / (reds[0] + reds[1] + reds[2] + reds[3]);
  a[t] = e0 * inv;
  a[t + 256] = e1 * inv;
}

// ---------------- o = a@v, o_pt = a@v_pts (+inverse rigid, norm) ---------------------
__global__ __launch_bounds__(256) void attn_v2(
    const float* __restrict__ attn, const float* __restrict__ kvb,
    const float* __restrict__ kvpts, const float* __restrict__ rot,
    const float* __restrict__ trans, float* __restrict__ feats) {
  const int it = blockIdx.x, h = blockIdx.y;   // grid (64, 8)
  const int i0 = it * 8;
  __shared__ float as[8][516];
  __shared__ float opt[8][36];
  const int t = threadIdx.x;
  for (int l = t; l < 8 * 128; l += 256) {
    int i = l >> 7, j4 = (l & 127) * 4;
    *(float4*)&as[i][j4] = *(const float4*)(attn + ((size_t)h * 512 + i0 + i) * 512 + j4);
  }
  __syncthreads();
  const int tx = t & 63, wid = t >> 6;
  const int iA = wid * 2;
  const bool do_p = tx < 36;
  const float* vbase = kvb + h * 512 + 256 + tx * 4;
  const float* pbase = kvpts + ((size_t)(h * 20 + 8)) * 3 + tx;
  float acc[2][4];
#pragma unroll
  for (int i = 0; i < 2; i++)
#pragma unroll
    for (int j = 0; j < 4; j++) acc[i][j] = 0.f;
  float accp[2] = {0.f, 0.f};

  for (int j = 0; j < 512; j += 4) {
    float4 aA = *(const float4*)&as[iA][j];
    float4 aB = *(const float4*)&as[iA + 1][j];
    const float fA[4] = {aA.x, aA.y, aA.z, aA.w};
    const float fB[4] = {aB.x, aB.y, aB.z, aB.w};
#pragma unroll
    for (int u = 0; u < 4; u++) {
      float4 v4 = *(const float4*)(vbase + (size_t)(j + u) * 4096);
      float vp = do_p ? pbase[(size_t)(j + u) * 480] : 0.f;
      acc[0][0] += fA[u] * v4.x; acc[0][1] += fA[u] * v4.y;
      acc[0][2] += fA[u] * v4.z; acc[0][3] += fA[u] * v4.w;
      acc[1][0] += fB[u] * v4.x; acc[1][1] += fB[u] * v4.y;
      acc[1][2] += fB[u] * v4.z; acc[1][3] += fB[u] * v4.w;
      accp[0] += fA[u] * vp;
      accp[1] += fB[u] * vp;
    }
  }
#pragma unroll
  for (int ii = 0; ii < 2; ii++) {
    int irow = i0 + iA + ii;
    float4 o4 = {acc[ii][0], acc[ii][1], acc[ii][2], acc[ii][3]};
    *(float4*)(feats + (size_t)irow * 2688 + h * 256 + tx * 4) = o4;
    if (do_p) opt[iA + ii][tx] = accp[ii];
  }
  __syncthreads();
  if (t < 96) {
    int i = t / 12, p = t % 12, irow = i0 + i;
    const float* R = rot + irow * 9;
    const float* tr = trans + irow * 3;
    float x = opt[i][p * 3 + 0] - tr[0];
    float y = opt[i][p * 3 + 1] - tr[1];
    float zz = opt[i][p * 3 + 2] - tr[2];
    float o0 = R[0] * x + R[3] * y + R[6] * zz;   // R^T v
    float o1 = R[1] * x + R[4] * y + R[7] * zz;
    float o2 = R[2] * x + R[5] * y + R[8] * zz;
    float nrm = sqrtf(o0 * o0 + o1 * o1 + o2 * o2 + 1e-8f);
    float* fr = feats + (size_t)irow * 2688 + 2048;
    fr[h * 12 + p]       = o0;
    fr[96 + h * 12 + p]  = o1;
    fr[192 + h * 12 + p] = o2;
    fr[288 + h * 12 + p] = nrm;
  }
}

// ---------------- o_pair = a @ pair_z (per query i) ----------------------------------
__global__ __launch_bounds__(256) void o_pair_kernel(
    const float* __restrict__ attn, const float* __restrict__ pairz,
    float* __restrict__ feats) {
  const int i = blockIdx.x;
  __shared__ float as[8][512];
  __shared__ float pzt[64][33];
  const int t = threadIdx.x;
  for (int l = t; l < 8 * 128; l += 256) {
    int hh = l >> 7, j4 = (l & 127) * 4;
    *(float4*)&as[hh][j4] = *(const float4*)(attn + ((size_t)hh * 512 + i) * 512 + j4);
  }
  const int h = t >> 5, d = t & 31;
  float acc = 0.f;
  for (int jt = 0; jt < 512; jt += 64) {
    __syncthreads();
    for (int l = t; l < 64 * 8; l += 256) {
      int j = l >> 3, d4 = (l & 7) * 4;
      float4 p4 = *(const float4*)(pairz + ((size_t)i * 512 + jt + j) * 32 + d4);
      pzt[j][d4 + 0] = p4.x; pzt[j][d4 + 1] = p4.y;
      pzt[j][d4 + 2] = p4.z; pzt[j][d4 + 3] = p4.w;
    }
    __syncthreads();
#pragma unroll
    for (int j = 0; j < 64; j += 4) {
      float4 a4 = *(const float4*)&as[h][jt + j];
      acc += a4.x * pzt[j][d] + a4.y * pzt[j + 1][d] + a4.z * pzt[j + 2][d] + a4.w * pzt[j + 3][d];
    }
  }
  feats[(size_t)i * 2688 + 2432 + h * 32 + d] = acc;
}

// ---------------- final GEMM: out = feats @ wo + bo (split-K=8, atomic) --------------
__global__ __launch_bounds__(256) void out_gemm_kernel(
    const float* __restrict__ feats, const float* __restrict__ wo,
    const float* __restrict__ bo, float* __restrict__ out) {
  __shared__ float As[16][64], Bs[16][64];
  int col0 = blockIdx.x * 64, row0 = blockIdx.y * 64;
  int k0 = blockIdx.z * 336;
  sgemm_tile64(feats, wo, blockIdx.z == 0 ? bo : nullptr, out,
               2688, 384, row0, col0, k0, k0 + 336, true, As, Bs);
}

extern "C" void kernel_launch(void* const* d_in, const int* in_sizes, int n_in,
                              void* d_out, int out_size, void* d_ws, size_t ws_size,
                              hipStream_t stream) {
  const float* s     = (const float*)d_in[0];
  const float* z     = (const float*)d_in[1];
  const float* rot   = (const float*)d_in[2];
  const float* trans = (const float*)d_in[3];
  const float* mask  = (const float*)d_in[4];
  const float* wq    = (const float*)d_in[5];
  const float* bq    = (const float*)d_in[6];
  const float* wkv   = (const float*)d_in[7];
  const float* bkv   = (const float*)d_in[8];
  const float* wqp   = (const float*)d_in[9];
  const float* bqp   = (const float*)d_in[10];
  const float* wkvp  = (const float*)d_in[11];
  const float* bkvp  = (const float*)d_in[12];
  const float* wb    = (const float*)d_in[13];
  const float* bb    = (const float*)d_in[14];
  const float* wz    = (const float*)d_in[15];
  const float* bz    = (const float*)d_in[16];
  const float* hwp   = (const float*)d_in[17];
  const float* wo    = (const float*)d_in[18];
  const float* bo    = (const float*)d_in[19];
  float* out = (float*)d_out;

  float* ws = (float*)d_ws;
  float* qb      = ws + OFF_Q;
  float* kvb     = ws + OFF_KV;
  float* qpraw   = ws + OFF_QPRAW;
  float* kvpraw  = ws + OFF_KVPRAW;
  float* qpts    = ws + OFF_QPTS;
  float* kvpts   = ws + OFF_KVPTS;
  float* bbias_t = ws + OFF_BBIAS;
  float* pairz   = ws + OFF_PAIRZ;
  float* attn    = ws + OFF_ATTN;
  float* feats   = ws + OFF_FEATS;
  float* wcat    = ws + OFF_WCAT;

  proj_kernel<<<dim3(107, 8), 256, 0, stream>>>(s, wq, bq, qb, wkv, bkv, kvb,
                                                wqp, bqp, qpraw, wkvp, bkvp, kvpraw);
  rigid_pts<<<448, 256, 0, stream>>>(qpraw, kvpraw, rot, trans, qpts, kvpts);
  prep_wcat<<<20, 256, 0, stream>>>(wb, wz, wcat);
  zpass2<<<1024, 256, 0, stream>>>(z, wcat, bb, bz, bbias_t, pairz);
  logits2<<<dim3(8, 8, 8), 256, 0, stream>>>(qb, kvb, qpts, kvpts, bbias_t, mask, hwp, attn);
  softmax_kernel<<<4096, 256, 0, stream>>>(attn);
  attn_v2<<<dim3(64, 8), 256, 0, stream>>>(attn, kvb, kvpts, rot, trans, feats);
  o_pair_kernel<<<512, 256, 0, stream>>>(attn, pairz, feats);
  (void)hipMemsetAsync(out, 0, (size_t)out_size * sizeof(float), stream);
  out_gemm_kernel<<<dim3(6, 8, 8), 256, 0, stream>>>(feats, wo, bo, out);
}

// Round 4
// 472.712 us; speedup vs baseline: 1.1581x; 1.0461x over previous
//
#include <hip/hip_runtime.h>

// TranslationIPA: B=1, N=512, CS=384, CZ=128, H=8, C=256, PQ=8, PV=12
// feats layout: [o 2048 | x 96 | y 96 | z 96 | norm 96 | o_pair 256] = 2688

// workspace float offsets
#define OFF_Q      0                         // 512*2048
#define OFF_KV     1048576                   // 512*4096
#define OFF_QPRAW  (OFF_KV + 2097152)        // 512*192
#define OFF_KVPRAW (OFF_QPRAW + 98304)       // 512*480
#define OFF_QPTS   (OFF_KVPRAW + 245760)     // 512*64*3
#define OFF_KVPTS  (OFF_QPTS + 98304)        // 512*160*3
#define OFF_BBIAS  (OFF_KVPTS + 245760)      // 8*512*512 (transposed: [h][i*512+j])
#define OFF_PAIRZ  (OFF_BBIAS + 2097152)     // 512*512*32
#define OFF_ATTN   (OFF_PAIRZ + 8388608)     // 8*512*512
#define OFF_FEATS  (OFF_ATTN + 2097152)      // 512*2688
#define OFF_WCAT   (OFF_FEATS + 1376256)     // 48*128 bf16 weights (as ushort)

typedef __attribute__((ext_vector_type(8))) short short8;   // 8 bf16 (4 VGPRs)
typedef __attribute__((ext_vector_type(4))) float f32x4;    // MFMA C/D

__device__ __forceinline__ unsigned short f2bf(float f) {   // RNE f32 -> bf16
  union { float f; unsigned u; } v; v.f = f;
  unsigned u = v.u;
  unsigned r = (u + 0x7fffu + ((u >> 16) & 1u)) >> 16;
  return (unsigned short)r;
}

// ---------------- generic 64x64 f32 GEMM tile --------------------------------------
__device__ __forceinline__ void sgemm_tile64(
    const float* __restrict__ A, const float* __restrict__ W,
    const float* bias /*nullable*/, float* __restrict__ Cout,
    const int K, const int Ncol, const int row0, const int col0,
    const int k0b, const int k1, const bool atomic,
    float (*As)[64], float (*Bs)[64]) {
  const int t  = threadIdx.x;
  const int tx = t & 15, ty = t >> 4;
  const int am = t >> 2, akq = (t & 3) << 2;
  const int bk = t >> 4, bn = (t & 15) << 2;
  float acc[4][4];
#pragma unroll
  for (int i = 0; i < 4; i++)
#pragma unroll
    for (int j = 0; j < 4; j++) acc[i][j] = 0.f;

  for (int k0 = k0b; k0 < k1; k0 += 16) {
    float4 a4 = *(const float4*)(A + (size_t)(row0 + am) * K + k0 + akq);
    float4 b4;
    {
      const float* wrow = W + (size_t)(k0 + bk) * Ncol;
      int col = col0 + bn;
      if (col + 3 < Ncol) b4 = *(const float4*)(wrow + col);
      else {
        b4.x = (col + 0 < Ncol) ? wrow[col + 0] : 0.f;
        b4.y = (col + 1 < Ncol) ? wrow[col + 1] : 0.f;
        b4.z = (col + 2 < Ncol) ? wrow[col + 2] : 0.f;
        b4.w = (col + 3 < Ncol) ? wrow[col + 3] : 0.f;
      }
    }
    __syncthreads();
    As[akq + 0][am] = a4.x; As[akq + 1][am] = a4.y;
    As[akq + 2][am] = a4.z; As[akq + 3][am] = a4.w;
    *(float4*)&Bs[bk][bn] = b4;
    __syncthreads();
#pragma unroll
    for (int kk = 0; kk < 16; kk++) {
      float4 av = *(const float4*)&As[kk][ty << 2];
      float4 bv = *(const float4*)&Bs[kk][tx << 2];
      acc[0][0] += av.x * bv.x; acc[0][1] += av.x * bv.y; acc[0][2] += av.x * bv.z; acc[0][3] += av.x * bv.w;
      acc[1][0] += av.y * bv.x; acc[1][1] += av.y * bv.y; acc[1][2] += av.y * bv.z; acc[1][3] += av.y * bv.w;
      acc[2][0] += av.z * bv.x; acc[2][1] += av.z * bv.y; acc[2][2] += av.z * bv.z; acc[2][3] += av.z * bv.w;
      acc[3][0] += av.w * bv.x; acc[3][1] += av.w * bv.y; acc[3][2] += av.w * bv.z; acc[3][3] += av.w * bv.w;
    }
  }
#pragma unroll
  for (int i = 0; i < 4; i++) {
    int row = row0 + (ty << 2) + i;
#pragma unroll
    for (int j = 0; j < 4; j++) {
      int col = col0 + (tx << 2) + j;
      if (col < Ncol) {
        float v = acc[i][j] + (bias ? bias[col] : 0.f);
        if (atomic) atomicAdd(&Cout[(size_t)row * Ncol + col], v);
        else Cout[(size_t)row * Ncol + col] = v;
      }
    }
  }
}

// ---------------- fused projections: s @ {wq,wkv,wqp,wkvp} --------------------------
__global__ __launch_bounds__(256) void proj_kernel(
    const float* __restrict__ s,
    const float* __restrict__ wq,  const float* __restrict__ bq,  float* __restrict__ qb,
    const float* __restrict__ wkv, const float* __restrict__ bkv, float* __restrict__ kvb,
    const float* __restrict__ wqp, const float* __restrict__ bqp, float* __restrict__ qpr,
    const float* __restrict__ wkvp,const float* __restrict__ bkvp,float* __restrict__ kvpr) {
  __shared__ float As[16][64], Bs[16][64];
  int bx = blockIdx.x, row0 = blockIdx.y * 64;
  const float *W, *bias; float* out; int Ncol, col0;
  if (bx < 32)      { W = wq;   bias = bq;   out = qb;   Ncol = 2048; col0 = bx * 64; }
  else if (bx < 96) { W = wkv;  bias = bkv;  out = kvb;  Ncol = 4096; col0 = (bx - 32) * 64; }
  else if (bx < 99) { W = wqp;  bias = bqp;  out = qpr;  Ncol = 192;  col0 = (bx - 96) * 64; }
  else              { W = wkvp; bias = bkvp; out = kvpr; Ncol = 480;  col0 = (bx - 99) * 64; }
  sgemm_tile64(s, W, bias, out, 384, Ncol, row0, col0, 0, 384, false, As, Bs);
}

// ---------------- rigid transform of point projections ------------------------------
__global__ __launch_bounds__(256) void rigid_pts(
    const float* __restrict__ qpraw, const float* __restrict__ kvpraw,
    const float* __restrict__ rot, const float* __restrict__ trans,
    float* __restrict__ qpts, float* __restrict__ kvpts) {
  int gid = blockIdx.x * 256 + threadIdx.x;  // 512*224 total, exact
  int n = gid / 224, r = gid % 224;
  const float* R  = rot + n * 9;
  const float* tr = trans + n * 3;
  float px, py, pz; float* dst;
  if (r < 64) {
    const float* src = qpraw + (size_t)n * 192;
    px = src[r]; py = src[64 + r]; pz = src[128 + r];
    dst = qpts + ((size_t)n * 64 + r) * 3;
  } else {
    int p = r - 64;
    const float* src = kvpraw + (size_t)n * 480;
    px = src[p]; py = src[160 + p]; pz = src[320 + p];
    dst = kvpts + ((size_t)n * 160 + p) * 3;
  }
  dst[0] = R[0] * px + R[1] * py + R[2] * pz + tr[0];
  dst[1] = R[3] * px + R[4] * py + R[5] * pz + tr[1];
  dst[2] = R[6] * px + R[7] * py + R[8] * pz + tr[2];
}

// ---------------- pack z-weights transposed bf16: wT[n][k], n<8 = wb*sqrt(1/3) ------
__global__ __launch_bounds__(256) void prep_wT(
    const float* __restrict__ wb, const float* __restrict__ wz,
    unsigned short* __restrict__ wT) {
  int l = blockIdx.x * 256 + threadIdx.x;  // 48*128 = 6144
  if (l < 6144) {
    int n = l >> 7, k = l & 127;
    float v = (n < 8) ? wb[k * 8 + n] * 0.5773502691896258f
                      : (n < 40 ? wz[k * 32 + (n - 8)] : 0.f);
    wT[l] = f2bf(v);
  }
}

// ---------------- z-pass v4: MFMA 16x16x32 bf16, weights resident in VGPRs ----------
// Each wave: one 16-row M-tile of the [262144 x 128] @ [128 x 48(pad)] GEMM.
// bbias_t[c*262144 + r] (c<8, includes sqrt(1/3) scale+bias); pairz[r*32 + c-8] (8<=c<40)
__global__ __launch_bounds__(256) void zpass_mfma(
    const float* __restrict__ z, const unsigned short* __restrict__ wT,
    const float* __restrict__ bb, const float* __restrict__ bz,
    float* __restrict__ bbias_t, float* __restrict__ pairz) {
  const int lane = threadIdx.x & 63;
  const int wave = threadIdx.x >> 6;
  const int quad = lane >> 4, m = lane & 15;
  const int tile = blockIdx.x * 4 + wave;     // 0..16383
  const int row0 = tile * 16;

  // B fragments: bf[nt][s] = wT[nt*16+m][s*32 + quad*8 .. +7]   (held in 48 VGPRs)
  short8 bf[3][4];
#pragma unroll
  for (int nt = 0; nt < 3; nt++)
#pragma unroll
    for (int s = 0; s < 4; s++)
      bf[nt][s] = *(const short8*)(wT + (size_t)(nt * 16 + m) * 128 + s * 32 + quad * 8);

  // per-lane output bias for each n-tile
  float bias[3];
#pragma unroll
  for (int nt = 0; nt < 3; nt++) {
    int c = nt * 16 + m;
    bias[nt] = (c < 8) ? 0.5773502691896258f * bb[c] : (c < 40 ? bz[c - 8] : 0.f);
  }

  f32x4 acc[3];
#pragma unroll
  for (int nt = 0; nt < 3; nt++) acc[nt] = (f32x4){0.f, 0.f, 0.f, 0.f};

  const float* zr = z + (size_t)(row0 + m) * 128 + quad * 8;
#pragma unroll
  for (int s = 0; s < 4; s++) {
    float4 a0 = *(const float4*)(zr + s * 32);
    float4 a1 = *(const float4*)(zr + s * 32 + 4);
    short8 af;
    af[0] = (short)f2bf(a0.x); af[1] = (short)f2bf(a0.y);
    af[2] = (short)f2bf(a0.z); af[3] = (short)f2bf(a0.w);
    af[4] = (short)f2bf(a1.x); af[5] = (short)f2bf(a1.y);
    af[6] = (short)f2bf(a1.z); af[7] = (short)f2bf(a1.w);
#pragma unroll
    for (int nt = 0; nt < 3; nt++)
      acc[nt] = __builtin_amdgcn_mfma_f32_16x16x32_bf16(af, bf[nt][s], acc[nt], 0, 0, 0);
  }

#pragma unroll
  for (int nt = 0; nt < 3; nt++) {
    const int c = nt * 16 + m;
#pragma unroll
    for (int r = 0; r < 4; r++) {
      const int row = row0 + quad * 4 + r;
      const float v = acc[nt][r] + bias[nt];
      if (c < 8)       bbias_t[(size_t)c * 262144 + row] = v;
      else if (c < 40) pairz[(size_t)row * 32 + (c - 8)] = v;
    }
  }
}

// ---------------- logits v2: 64x64 tile, 4x4 reg tile, transposed LDS frags ----------
__global__ __launch_bounds__(256) void logits2(
    const float* __restrict__ qb, const float* __restrict__ kvb,
    const float* __restrict__ qpts, const float* __restrict__ kvpts,
    const float* __restrict__ bbias_t, const float* __restrict__ mask,
    const float* __restrict__ hwp, float* __restrict__ attn) {
  const int jt = blockIdx.x, it = blockIdx.y, h = blockIdx.z;
  const int i0 = it * 64, j0 = jt * 64;
  __shared__ float qT[32][68], kT[32][68];
  __shared__ float qp[64][25], kp[64][25];
  __shared__ float qp2[64], kp2[64];
  const int t = threadIdx.x, tx = t & 15, ty = t >> 4;

  for (int l = t; l < 64 * 24; l += 256) {
    int r = l / 24, w = l % 24;
    qp[r][w] = qpts[((size_t)(i0 + r) * 64 + h * 8) * 3 + w];
    kp[r][w] = kvpts[((size_t)(j0 + r) * 160 + h * 20) * 3 + w];
  }
  __syncthreads();
  if (t < 64) {
    float s1 = 0.f, s2 = 0.f;
#pragma unroll
    for (int w = 0; w < 24; w++) { s1 += qp[t][w] * qp[t][w]; s2 += kp[t][w] * kp[t][w]; }
    qp2[t] = s1; kp2[t] = s2;
  }

  float acc[4][4];
#pragma unroll
  for (int i = 0; i < 4; i++)
#pragma unroll
    for (int j = 0; j < 4; j++) acc[i][j] = 0.f;

  const int si = t & 63, sc = (t >> 6) * 4;
  for (int kc = 0; kc < 256; kc += 32) {
    __syncthreads();
    const float* qrow = qb  + (size_t)(i0 + si) * 2048 + h * 256 + kc;
    const float* krow = kvb + (size_t)(j0 + si) * 4096 + h * 512 + kc;
    float4 a0 = *(const float4*)(qrow + sc);
    float4 a1 = *(const float4*)(qrow + sc + 16);
    float4 b0 = *(const float4*)(krow + sc);
    float4 b1 = *(const float4*)(krow + sc + 16);
    qT[sc + 0][si]  = a0.x; qT[sc + 1][si]  = a0.y; qT[sc + 2][si]  = a0.z; qT[sc + 3][si]  = a0.w;
    qT[sc + 16][si] = a1.x; qT[sc + 17][si] = a1.y; qT[sc + 18][si] = a1.z; qT[sc + 19][si] = a1.w;
    kT[sc + 0][si]  = b0.x; kT[sc + 1][si]  = b0.y; kT[sc + 2][si]  = b0.z; kT[sc + 3][si]  = b0.w;
    kT[sc + 16][si] = b1.x; kT[sc + 17][si] = b1.y; kT[sc + 18][si] = b1.z; kT[sc + 19][si] = b1.w;
    __syncthreads();
#pragma unroll
    for (int k = 0; k < 32; k++) {
      float4 a4 = *(const float4*)&qT[k][ty << 2];
      float4 b4 = *(const float4*)&kT[k][tx << 2];
      acc[0][0] += a4.x * b4.x; acc[0][1] += a4.x * b4.y; acc[0][2] += a4.x * b4.z; acc[0][3] += a4.x * b4.w;
      acc[1][0] += a4.y * b4.x; acc[1][1] += a4.y * b4.y; acc[1][2] += a4.y * b4.z; acc[1][3] += a4.y * b4.w;
      acc[2][0] += a4.z * b4.x; acc[2][1] += a4.z * b4.y; acc[2][2] += a4.z * b4.z; acc[2][3] += a4.z * b4.w;
      acc[3][0] += a4.w * b4.x; acc[3][1] += a4.w * b4.y; acc[3][2] += a4.w * b4.z; acc[3][3] += a4.w * b4.w;
    }
  }

  const float c1 = 0.03608439182435161f;                    // 1/sqrt(768)
  const float hw = log1pf(expf(hwp[h])) * 0.09622504486493764f;  // softplus * sqrt(1/108)
  float4 mj4 = *(const float4*)(mask + j0 + tx * 4);
  const float mjv[4] = {mj4.x, mj4.y, mj4.z, mj4.w};
#pragma unroll
  for (int ii = 0; ii < 4; ii++) {
    const int i = i0 + (ty << 2) + ii;
    const float mi = mask[i];
    float4 bb4 = *(const float4*)(bbias_t + (size_t)h * 262144 + (size_t)i * 512 + j0 + tx * 4);
    const float bbv[4] = {bb4.x, bb4.y, bb4.z, bb4.w};
    const float qi2 = qp2[(ty << 2) + ii];
    float res[4];
#pragma unroll
    for (int jj = 0; jj < 4; jj++) {
      float cross = 0.f;
#pragma unroll
      for (int w = 0; w < 24; w++) cross += qp[(ty << 2) + ii][w] * kp[(tx << 2) + jj][w];
      float pt = qi2 + kp2[(tx << 2) + jj] - 2.f * cross;
      res[jj] = c1 * acc[ii][jj] + bbv[jj] - 0.5f * hw * pt + 100000.f * (mi * mjv[jj] - 1.f);
    }
    float4 outv = {res[0], res[1], res[2], res[3]};
    *(float4*)(attn + ((size_t)h * 512 + i) * 512 + j0 + tx * 4) = outv;
  }
}

// ---------------- row softmax over j (512), in place --------------------------------
__global__ __launch_bounds__(256) void softmax_kernel(float* __restrict__ attn) {
  float* a = attn + (size_t)blockIdx.x * 512;
  const int t = threadIdx.x;
  float v0 = a[t], v1 = a[t + 256];
  __shared__ float redm[4], reds[4];
  float m = fmaxf(v0, v1);
#pragma unroll
  for (int o = 1; o < 64; o <<= 1) m = fmaxf(m, __shfl_xor(m, o));
  if ((t & 63) == 0) redm[t >> 6] = m;
  __syncthreads();
  m = fmaxf(fmaxf(redm[0], redm[1]), fmaxf(redm[2], redm[3]));
  float e0 = expf(v0 - m), e1 = expf(v1 - m);
  float s = e0 + e1;
#pragma unroll
  for (int o = 1; o < 64; o <<= 1) s += __shfl_xor(s, o);
  if ((t & 63) == 0) reds[t >> 6] = s;
  __syncthreads();
  float inv = 1.0f / (reds[0] + reds[1] + reds[2] + reds[3]);
  a[t] = e0 * inv;
  a[t + 256] = e1 * inv;
}

// ---------------- o = a@v, o_pt = a@v_pts (+inverse rigid, norm) ---------------------
__global__ __launch_bounds__(256) void attn_v2(
    const float* __restrict__ attn, const float* __restrict__ kvb,
    const float* __restrict__ kvpts, const float* __restrict__ rot,
    const float* __restrict__ trans, float* __restrict__ feats) {
  const int it = blockIdx.x, h = blockIdx.y;   // grid (64, 8)
  const int i0 = it * 8;
  __shared__ float as[8][516];
  __shared__ float opt[8][36];
  const int t = threadIdx.x;
  for (int l = t; l < 8 * 128; l += 256) {
    int i = l >> 7, j4 = (l & 127) * 4;
    *(float4*)&as[i][j4] = *(const float4*)(attn + ((size_t)h * 512 + i0 + i) * 512 + j4);
  }
  __syncthreads();
  const int tx = t & 63, wid = t >> 6;
  const int iA = wid * 2;
  const bool do_p = tx < 36;
  const float* vbase = kvb + h * 512 + 256 + tx * 4;
  const float* pbase = kvpts + ((size_t)(h * 20 + 8)) * 3 + tx;
  float acc[2][4];
#pragma unroll
  for (int i = 0; i < 2; i++)
#pragma unroll
    for (int j = 0; j < 4; j++) acc[i][j] = 0.f;
  float accp[2] = {0.f, 0.f};

  for (int j = 0; j < 512; j += 4) {
    float4 aA = *(const float4*)&as[iA][j];
    float4 aB = *(const float4*)&as[iA + 1][j];
    const float fA[4] = {aA.x, aA.y, aA.z, aA.w};
    const float fB[4] = {aB.x, aB.y, aB.z, aB.w};
#pragma unroll
    for (int u = 0; u < 4; u++) {
      float4 v4 = *(const float4*)(vbase + (size_t)(j + u) * 4096);
      float vp = do_p ? pbase[(size_t)(j + u) * 480] : 0.f;
      acc[0][0] += fA[u] * v4.x; acc[0][1] += fA[u] * v4.y;
      acc[0][2] += fA[u] * v4.z; acc[0][3] += fA[u] * v4.w;
      acc[1][0] += fB[u] * v4.x; acc[1][1] += fB[u] * v4.y;
      acc[1][2] += fB[u] * v4.z; acc[1][3] += fB[u] * v4.w;
      accp[0] += fA[u] * vp;
      accp[1] += fB[u] * vp;
    }
  }
#pragma unroll
  for (int ii = 0; ii < 2; ii++) {
    int irow = i0 + iA + ii;
    float4 o4 = {acc[ii][0], acc[ii][1], acc[ii][2], acc[ii][3]};
    *(float4*)(feats + (size_t)irow * 2688 + h * 256 + tx * 4) = o4;
    if (do_p) opt[iA + ii][tx] = accp[ii];
  }
  __syncthreads();
  if (t < 96) {
    int i = t / 12, p = t % 12, irow = i0 + i;
    const float* R = rot + irow * 9;
    const float* tr = trans + irow * 3;
    float x = opt[i][p * 3 + 0] - tr[0];
    float y = opt[i][p * 3 + 1] - tr[1];
    float zz = opt[i][p * 3 + 2] - tr[2];
    float o0 = R[0] * x + R[3] * y + R[6] * zz;   // R^T v
    float o1 = R[1] * x + R[4] * y + R[7] * zz;
    float o2 = R[2] * x + R[5] * y + R[8] * zz;
    float nrm = sqrtf(o0 * o0 + o1 * o1 + o2 * o2 + 1e-8f);
    float* fr = feats + (size_t)irow * 2688 + 2048;
    fr[h * 12 + p]       = o0;
    fr[96 + h * 12 + p]  = o1;
    fr[192 + h * 12 + p] = o2;
    fr[288 + h * 12 + p] = nrm;
  }
}

// ---------------- o_pair = a @ pair_z (per query i) ----------------------------------
__global__ __launch_bounds__(256) void o_pair_kernel(
    const float* __restrict__ attn, const float* __restrict__ pairz,
    float* __restrict__ feats) {
  const int i = blockIdx.x;
  __shared__ float as[8][512];
  __shared__ float pzt[64][33];
  const int t = threadIdx.x;
  for (int l = t; l < 8 * 128; l += 256) {
    int hh = l >> 7, j4 = (l & 127) * 4;
    *(float4*)&as[hh][j4] = *(const float4*)(attn + ((size_t)hh * 512 + i) * 512 + j4);
  }
  const int h = t >> 5, d = t & 31;
  float acc = 0.f;
  for (int jt = 0; jt < 512; jt += 64) {
    __syncthreads();
    for (int l = t; l < 64 * 8; l += 256) {
      int j = l >> 3, d4 = (l & 7) * 4;
      float4 p4 = *(const float4*)(pairz + ((size_t)i * 512 + jt + j) * 32 + d4);
      pzt[j][d4 + 0] = p4.x; pzt[j][d4 + 1] = p4.y;
      pzt[j][d4 + 2] = p4.z; pzt[j][d4 + 3] = p4.w;
    }
    __syncthreads();
#pragma unroll
    for (int j = 0; j < 64; j += 4) {
      float4 a4 = *(const float4*)&as[h][jt + j];
      acc += a4.x * pzt[j][d] + a4.y * pzt[j + 1][d] + a4.z * pzt[j + 2][d] + a4.w * pzt[j + 3][d];
    }
  }
  feats[(size_t)i * 2688 + 2432 + h * 32 + d] = acc;
}

// ---------------- final GEMM: out = feats @ wo + bo (split-K=8, atomic) --------------
__global__ __launch_bounds__(256) void out_gemm_kernel(
    const float* __restrict__ feats, const float* __restrict__ wo,
    const float* __restrict__ bo, float* __restrict__ out) {
  __shared__ float As[16][64], Bs[16][64];
  int col0 = blockIdx.x * 64, row0 = blockIdx.y * 64;
  int k0 = blockIdx.z * 336;
  sgemm_tile64(feats, wo, blockIdx.z == 0 ? bo : nullptr, out,
               2688, 384, row0, col0, k0, k0 + 336, true, As, Bs);
}

extern "C" void kernel_launch(void* const* d_in, const int* in_sizes, int n_in,
                              void* d_out, int out_size, void* d_ws, size_t ws_size,
                              hipStream_t stream) {
  const float* s     = (const float*)d_in[0];
  const float* z     = (const float*)d_in[1];
  const float* rot   = (const float*)d_in[2];
  const float* trans = (const float*)d_in[3];
  const float* mask  = (const float*)d_in[4];
  const float* wq    = (const float*)d_in[5];
  const float* bq    = (const float*)d_in[6];
  const float* wkv   = (const float*)d_in[7];
  const float* bkv   = (const float*)d_in[8];
  const float* wqp   = (const float*)d_in[9];
  const float* bqp   = (const float*)d_in[10];
  const float* wkvp  = (const float*)d_in[11];
  const float* bkvp  = (const float*)d_in[12];
  const float* wb    = (const float*)d_in[13];
  const float* bb    = (const float*)d_in[14];
  const float* wz    = (const float*)d_in[15];
  const float* bz    = (const float*)d_in[16];
  const float* hwp   = (const float*)d_in[17];
  const float* wo    = (const float*)d_in[18];
  const float* bo    = (const float*)d_in[19];
  float* out = (float*)d_out;

  float* ws = (float*)d_ws;
  float* qb      = ws + OFF_Q;
  float* kvb     = ws + OFF_KV;
  float* qpraw   = ws + OFF_QPRAW;
  float* kvpraw  = ws + OFF_KVPRAW;
  float* qpts    = ws + OFF_QPTS;
  float* kvpts   = ws + OFF_KVPTS;
  float* bbias_t = ws + OFF_BBIAS;
  float* pairz   = ws + OFF_PAIRZ;
  float* attn    = ws + OFF_ATTN;
  float* feats   = ws + OFF_FEATS;
  unsigned short* wT = (unsigned short*)(ws + OFF_WCAT);

  proj_kernel<<<dim3(107, 8), 256, 0, stream>>>(s, wq, bq, qb, wkv, bkv, kvb,
                                                wqp, bqp, qpraw, wkvp, bkvp, kvpraw);
  rigid_pts<<<448, 256, 0, stream>>>(qpraw, kvpraw, rot, trans, qpts, kvpts);
  prep_wT<<<24, 256, 0, stream>>>(wb, wz, wT);
  zpass_mfma<<<4096, 256, 0, stream>>>(z, wT, bb, bz, bbias_t, pairz);
  logits2<<<dim3(8, 8, 8), 256, 0, stream>>>(qb, kvb, qpts, kvpts, bbias_t, mask, hwp, attn);
  softmax_kernel<<<4096, 256, 0, stream>>>(attn);
  attn_v2<<<dim3(64, 8), 256, 0, stream>>>(attn, kvb, kvpts, rot, trans, feats);
  o_pair_kernel<<<512, 256, 0, stream>>>(attn, pairz, feats);
  (void)hipMemsetAsync(out, 0, (size_t)out_size * sizeof(float), stream);
  out_gemm_kernel<<<dim3(6, 8, 8), 256, 0, stream>>>(feats, wo, bo, out);
}

// Round 5
// 431.674 us; speedup vs baseline: 1.2682x; 1.0951x over previous
//
#include <hip/hip_runtime.h>

// TranslationIPA: B=1, N=512, CS=384, CZ=128, H=8, C=256, PQ=8, PV=12
// feats layout: [o 2048 | x 96 | y 96 | z 96 | norm 96 | o_pair 256] = 2688

// workspace float offsets
#define OFF_QBH    0                         // 512*2048 bf16 (as ushort) = 524288 fl
#define OFF_KBH    524288                    // 512*2048 bf16
#define OFF_VB     1048576                   // 512*2048 fp32 (v compact [i][h*256+c])
#define OFF_QPRAW  2097152                   // 512*192
#define OFF_KVPRAW 2195456                   // 512*480
#define OFF_QPTS   2441216                   // 512*64*3
#define OFF_KVPTS  2539520                   // 512*160*3
#define OFF_BBIAS  2785280                   // 8*512*512 (transposed: [h][i*512+j])
#define OFF_PAIRZ  4882432                   // 512*512*32
#define OFF_ATTN   13271040                  // 8*512*512
#define OFF_FEATS  15368192                  // 512*2688
#define OFF_WCAT   16744448                  // 48*128 bf16 z-weights
#define OFF_WTALL  16747520                  // 6848*384 bf16 = 1314816 fl

typedef __attribute__((ext_vector_type(8))) short short8;   // 8 bf16 (4 VGPRs)
typedef __attribute__((ext_vector_type(4))) float f32x4;    // MFMA C/D

__device__ __forceinline__ unsigned short f2bf(float f) {   // RNE f32 -> bf16
  union { float f; unsigned u; } v; v.f = f;
  unsigned u = v.u;
  unsigned r = (u + 0x7fffu + ((u >> 16) & 1u)) >> 16;
  return (unsigned short)r;
}
__device__ __forceinline__ float bf2f(unsigned short h) {
  union { unsigned u; float f; } v; v.u = ((unsigned)h) << 16; return v.f;
}
__device__ __forceinline__ short8 pack8(float4 a, float4 b) {
  short8 r;
  r[0] = (short)f2bf(a.x); r[1] = (short)f2bf(a.y);
  r[2] = (short)f2bf(a.z); r[3] = (short)f2bf(a.w);
  r[4] = (short)f2bf(b.x); r[5] = (short)f2bf(b.y);
  r[6] = (short)f2bf(b.z); r[7] = (short)f2bf(b.w);
  return r;
}

// ---------------- generic 64x64 f32 GEMM tile (for out_gemm) ------------------------
__device__ __forceinline__ void sgemm_tile64(
    const float* __restrict__ A, const float* __restrict__ W,
    const float* bias, float* __restrict__ Cout,
    const int K, const int Ncol, const int row0, const int col0,
    const int k0b, const int k1, const bool atomic,
    float (*As)[64], float (*Bs)[64]) {
  const int t  = threadIdx.x;
  const int tx = t & 15, ty = t >> 4;
  const int am = t >> 2, akq = (t & 3) << 2;
  const int bk = t >> 4, bn = (t & 15) << 2;
  float acc[4][4];
#pragma unroll
  for (int i = 0; i < 4; i++)
#pragma unroll
    for (int j = 0; j < 4; j++) acc[i][j] = 0.f;

  for (int k0 = k0b; k0 < k1; k0 += 16) {
    float4 a4 = *(const float4*)(A + (size_t)(row0 + am) * K + k0 + akq);
    float4 b4 = *(const float4*)(W + (size_t)(k0 + bk) * Ncol + col0 + bn);
    __syncthreads();
    As[akq + 0][am] = a4.x; As[akq + 1][am] = a4.y;
    As[akq + 2][am] = a4.z; As[akq + 3][am] = a4.w;
    *(float4*)&Bs[bk][bn] = b4;
    __syncthreads();
#pragma unroll
    for (int kk = 0; kk < 16; kk++) {
      float4 av = *(const float4*)&As[kk][ty << 2];
      float4 bv = *(const float4*)&Bs[kk][tx << 2];
      acc[0][0] += av.x * bv.x; acc[0][1] += av.x * bv.y; acc[0][2] += av.x * bv.z; acc[0][3] += av.x * bv.w;
      acc[1][0] += av.y * bv.x; acc[1][1] += av.y * bv.y; acc[1][2] += av.y * bv.z; acc[1][3] += av.y * bv.w;
      acc[2][0] += av.z * bv.x; acc[2][1] += av.z * bv.y; acc[2][2] += av.z * bv.z; acc[2][3] += av.z * bv.w;
      acc[3][0] += av.w * bv.x; acc[3][1] += av.w * bv.y; acc[3][2] += av.w * bv.z; acc[3][3] += av.w * bv.w;
    }
  }
#pragma unroll
  for (int i = 0; i < 4; i++) {
    int row = row0 + (ty << 2) + i;
#pragma unroll
    for (int j = 0; j < 4; j++) {
      int col = col0 + (tx << 2) + j;
      float v = acc[i][j] + (bias ? bias[col] : 0.f);
      if (atomic) atomicAdd(&Cout[(size_t)row * Ncol + col], v);
      else Cout[(size_t)row * Ncol + col] = v;
    }
  }
}

// ---------------- prep: transpose all proj weights to bf16 wT_all[6848][384] --------
// rows: [wq^T 0..2047 | wkv^T 2048..6143 | wqp^T 6144..6335 | wkvp^T 6336..6847(480 real)]
__global__ __launch_bounds__(256) void prep_wT_all(
    const float* __restrict__ wq, const float* __restrict__ wkv,
    const float* __restrict__ wqp, const float* __restrict__ wkvp,
    unsigned short* __restrict__ wTall) {
  const int ntile = blockIdx.x, kt = blockIdx.y;   // 107 x 6
  const float* src; int Nsrc, nloc0;
  const int ng0 = ntile * 64;
  if (ntile < 32)      { src = wq;   Nsrc = 2048; nloc0 = ng0; }
  else if (ntile < 96) { src = wkv;  Nsrc = 4096; nloc0 = ng0 - 2048; }
  else if (ntile < 99) { src = wqp;  Nsrc = 192;  nloc0 = ng0 - 6144; }
  else                 { src = wkvp; Nsrc = 480;  nloc0 = ng0 - 6336; }
  __shared__ float tile[64][65];
  const int t = threadIdx.x;
  const int r = t >> 2, cs = (t & 3) * 16;
#pragma unroll
  for (int i = 0; i < 16; i += 4) {
    int n = nloc0 + cs + i;
    float4 v;
    if (n + 3 < Nsrc) v = *(const float4*)(src + (size_t)(kt * 64 + r) * Nsrc + n);
    else {
      v.x = (n + 0 < Nsrc) ? src[(size_t)(kt * 64 + r) * Nsrc + n + 0] : 0.f;
      v.y = (n + 1 < Nsrc) ? src[(size_t)(kt * 64 + r) * Nsrc + n + 1] : 0.f;
      v.z = (n + 2 < Nsrc) ? src[(size_t)(kt * 64 + r) * Nsrc + n + 2] : 0.f;
      v.w = (n + 3 < Nsrc) ? src[(size_t)(kt * 64 + r) * Nsrc + n + 3] : 0.f;
    }
    tile[r][cs + i + 0] = v.x; tile[r][cs + i + 1] = v.y;
    tile[r][cs + i + 2] = v.z; tile[r][cs + i + 3] = v.w;
  }
  __syncthreads();
  const int nr = t >> 2, ks = (t & 3) * 16;
  unsigned short ov[16];
#pragma unroll
  for (int i = 0; i < 16; i++) ov[i] = f2bf(tile[ks + i][nr]);
  unsigned short* dst = wTall + (size_t)(ng0 + nr) * 384 + kt * 64 + ks;
  *(uint4*)(dst) = *(const uint4*)&ov[0];
  *(uint4*)(dst + 8) = *(const uint4*)&ov[8];
}

// ---------------- proj via MFMA: s @ {wq,wkv,wqp,wkvp}, K=384 ------------------------
// outputs: qbh bf16 [i][h*256+c], kbh bf16 [i][h*256+c], vb fp32 [i][h*256+c],
//          qpraw fp32 [i][192], kvpraw fp32 [i][480]
__global__ __launch_bounds__(256) void proj_mfma(
    const float* __restrict__ s, const unsigned short* __restrict__ wTall,
    const float* __restrict__ bq, const float* __restrict__ bkv,
    const float* __restrict__ bqp, const float* __restrict__ bkvp,
    unsigned short* __restrict__ qbh, unsigned short* __restrict__ kbh,
    float* __restrict__ vb, float* __restrict__ qpraw, float* __restrict__ kvpraw) {
  const int bx = blockIdx.x, row0 = blockIdx.y * 64;
  const int lane = threadIdx.x & 63, wv = threadIdx.x >> 6;
  const int quad = lane >> 4, m = lane & 15;
  const int n0 = bx * 64;
  const float* srow = s + (size_t)(row0 + wv * 16 + m) * 384;
  f32x4 acc[4];
#pragma unroll
  for (int nt = 0; nt < 4; nt++) acc[nt] = (f32x4){0.f, 0.f, 0.f, 0.f};

#pragma unroll
  for (int ksx = 0; ksx < 12; ksx++) {
    const int c0 = ksx * 32 + quad * 8;
    float4 a0 = *(const float4*)(srow + c0);
    float4 a1 = *(const float4*)(srow + c0 + 4);
    short8 af = pack8(a0, a1);
#pragma unroll
    for (int nt = 0; nt < 4; nt++) {
      short8 bf = *(const short8*)(wTall + (size_t)(n0 + nt * 16 + m) * 384 + c0);
      acc[nt] = __builtin_amdgcn_mfma_f32_16x16x32_bf16(af, bf, acc[nt], 0, 0, 0);
    }
  }

  const int rbase = row0 + wv * 16 + quad * 4;
#pragma unroll
  for (int nt = 0; nt < 4; nt++) {
    const int col = n0 + nt * 16 + m;
    if (n0 < 2048) {                 // q -> bf16
      const float bias = bq[col];
#pragma unroll
      for (int r = 0; r < 4; r++)
        qbh[(size_t)(rbase + r) * 2048 + col] = f2bf(acc[nt][r] + bias);
    } else if (n0 < 6144) {          // kv
      const int ckv = col - 2048;
      const float bias = bkv[ckv];
      const int hh = ckv >> 9, c = ckv & 511;
      if (c < 256) {                 // k -> bf16
#pragma unroll
        for (int r = 0; r < 4; r++)
          kbh[(size_t)(rbase + r) * 2048 + hh * 256 + c] = f2bf(acc[nt][r] + bias);
      } else {                       // v -> fp32 compact
#pragma unroll
        for (int r = 0; r < 4; r++)
          vb[(size_t)(rbase + r) * 2048 + hh * 256 + (c - 256)] = acc[nt][r] + bias;
      }
    } else if (n0 < 6336) {          // q-points raw
      const int cq = col - 6144;
      const float bias = bqp[cq];
#pragma unroll
      for (int r = 0; r < 4; r++)
        qpraw[(size_t)(rbase + r) * 192 + cq] = acc[nt][r] + bias;
    } else {                         // kv-points raw (480 real cols)
      const int ck = col - 6336;
      if (ck < 480) {
        const float bias = bkvp[ck];
#pragma unroll
        for (int r = 0; r < 4; r++)
          kvpraw[(size_t)(rbase + r) * 480 + ck] = acc[nt][r] + bias;
      }
    }
  }
}

// ---------------- rigid transform of point projections ------------------------------
__global__ __launch_bounds__(256) void rigid_pts(
    const float* __restrict__ qpraw, const float* __restrict__ kvpraw,
    const float* __restrict__ rot, const float* __restrict__ trans,
    float* __restrict__ qpts, float* __restrict__ kvpts) {
  int gid = blockIdx.x * 256 + threadIdx.x;  // 512*224 total, exact
  int n = gid / 224, r = gid % 224;
  const float* R  = rot + n * 9;
  const float* tr = trans + n * 3;
  float px, py, pz; float* dst;
  if (r < 64) {
    const float* src = qpraw + (size_t)n * 192;
    px = src[r]; py = src[64 + r]; pz = src[128 + r];
    dst = qpts + ((size_t)n * 64 + r) * 3;
  } else {
    int p = r - 64;
    const float* src = kvpraw + (size_t)n * 480;
    px = src[p]; py = src[160 + p]; pz = src[320 + p];
    dst = kvpts + ((size_t)n * 160 + p) * 3;
  }
  dst[0] = R[0] * px + R[1] * py + R[2] * pz + tr[0];
  dst[1] = R[3] * px + R[4] * py + R[5] * pz + tr[1];
  dst[2] = R[6] * px + R[7] * py + R[8] * pz + tr[2];
}

// ---------------- pack z-weights transposed bf16: wT[n][k], n<8 = wb*sqrt(1/3) ------
__global__ __launch_bounds__(256) void prep_wT(
    const float* __restrict__ wb, const float* __restrict__ wz,
    unsigned short* __restrict__ wT) {
  int l = blockIdx.x * 256 + threadIdx.x;  // 48*128 = 6144
  if (l < 6144) {
    int n = l >> 7, k = l & 127;
    float v = (n < 8) ? wb[k * 8 + n] * 0.5773502691896258f
                      : (n < 40 ? wz[k * 32 + (n - 8)] : 0.f);
    wT[l] = f2bf(v);
  }
}

// ---------------- z-pass: MFMA 16x16x32 bf16, weights resident in VGPRs -------------
__global__ __launch_bounds__(256) void zpass_mfma(
    const float* __restrict__ z, const unsigned short* __restrict__ wT,
    const float* __restrict__ bb, const float* __restrict__ bz,
    float* __restrict__ bbias_t, float* __restrict__ pairz) {
  const int lane = threadIdx.x & 63;
  const int wave = threadIdx.x >> 6;
  const int quad = lane >> 4, m = lane & 15;
  const int tile = blockIdx.x * 4 + wave;     // 0..16383
  const int row0 = tile * 16;

  short8 bf[3][4];
#pragma unroll
  for (int nt = 0; nt < 3; nt++)
#pragma unroll
    for (int s = 0; s < 4; s++)
      bf[nt][s] = *(const short8*)(wT + (size_t)(nt * 16 + m) * 128 + s * 32 + quad * 8);

  float bias[3];
#pragma unroll
  for (int nt = 0; nt < 3; nt++) {
    int c = nt * 16 + m;
    bias[nt] = (c < 8) ? 0.5773502691896258f * bb[c] : (c < 40 ? bz[c - 8] : 0.f);
  }

  f32x4 acc[3];
#pragma unroll
  for (int nt = 0; nt < 3; nt++) acc[nt] = (f32x4){0.f, 0.f, 0.f, 0.f};

  const float* zr = z + (size_t)(row0 + m) * 128 + quad * 8;
#pragma unroll
  for (int s = 0; s < 4; s++) {
    float4 a0 = *(const float4*)(zr + s * 32);
    float4 a1 = *(const float4*)(zr + s * 32 + 4);
    short8 af = pack8(a0, a1);
#pragma unroll
    for (int nt = 0; nt < 3; nt++)
      acc[nt] = __builtin_amdgcn_mfma_f32_16x16x32_bf16(af, bf[nt][s], acc[nt], 0, 0, 0);
  }

#pragma unroll
  for (int nt = 0; nt < 3; nt++) {
    const int c = nt * 16 + m;
#pragma unroll
    for (int r = 0; r < 4; r++) {
      const int row = row0 + quad * 4 + r;
      const float v = acc[nt][r] + bias[nt];
      if (c < 8)       bbias_t[(size_t)c * 262144 + row] = v;
      else if (c < 40) pairz[(size_t)row * 32 + (c - 8)] = v;
    }
  }
}

// ---------------- logits via MFMA: QK^T + hi/lo-split point cross-term ---------------
__global__ __launch_bounds__(256) void logits_mfma(
    const unsigned short* __restrict__ qbh, const unsigned short* __restrict__ kbh,
    const float* __restrict__ qpts, const float* __restrict__ kvpts,
    const float* __restrict__ bbias_t, const float* __restrict__ mask,
    const float* __restrict__ hwp, float* __restrict__ attn) {
  const int jt = blockIdx.x, it = blockIdx.y, h = blockIdx.z;
  const int i0 = it * 64, j0 = jt * 64;
  __shared__ unsigned short qph[64 * 32], qpl[64 * 32];
  __shared__ unsigned short kph[64 * 32], kpl[64 * 32];
  __shared__ float qp2[64], kp2[64];
  const int t = threadIdx.x;
  {
    const int r = t & 63, g = t >> 6;
    const float* qsrc = qpts + ((size_t)(i0 + r) * 64 + h * 8) * 3;
    const float* ksrc = kvpts + ((size_t)(j0 + r) * 160 + h * 20) * 3;
#pragma unroll
    for (int kk = 0; kk < 8; kk++) {
      const int w = g * 8 + kk;
      const float xq = (w < 24) ? qsrc[w] : 0.f;
      const float xk = (w < 24) ? ksrc[w] : 0.f;
      unsigned short qh = f2bf(xq);
      qph[r * 32 + w] = qh; qpl[r * 32 + w] = f2bf(xq - bf2f(qh));
      unsigned short kh = f2bf(xk);
      kph[r * 32 + w] = kh; kpl[r * 32 + w] = f2bf(xk - bf2f(kh));
    }
    if (g == 0) { float s1 = 0.f; for (int w = 0; w < 24; w++) s1 += qsrc[w] * qsrc[w]; qp2[r] = s1; }
    if (g == 1) { float s2 = 0.f; for (int w = 0; w < 24; w++) s2 += ksrc[w] * ksrc[w]; kp2[r] = s2; }
  }
  __syncthreads();

  const int lane = t & 63, wv = t >> 6;
  const int quad = lane >> 4, m = lane & 15;
  const int ib = wv * 16;   // wave's i-sub-tile

  // ---- QK^T main loop (K=256, 8 steps) ----
  f32x4 acc[4];
#pragma unroll
  for (int nt = 0; nt < 4; nt++) acc[nt] = (f32x4){0.f, 0.f, 0.f, 0.f};
  const unsigned short* qrow = qbh + (size_t)(i0 + ib + m) * 2048 + h * 256;
#pragma unroll
  for (int s = 0; s < 8; s++) {
    short8 af = *(const short8*)(qrow + s * 32 + quad * 8);
#pragma unroll
    for (int nt = 0; nt < 4; nt++) {
      short8 bfr = *(const short8*)(kbh + (size_t)(j0 + nt * 16 + m) * 2048 + h * 256 + s * 32 + quad * 8);
      acc[nt] = __builtin_amdgcn_mfma_f32_16x16x32_bf16(af, bfr, acc[nt], 0, 0, 0);
    }
  }

  // ---- point cross-term via hi/lo split MFMAs ----
  short8 aqh = *(const short8*)&qph[(ib + m) * 32 + quad * 8];
  short8 aql = *(const short8*)&qpl[(ib + m) * 32 + quad * 8];
  f32x4 accp[4];
#pragma unroll
  for (int nt = 0; nt < 4; nt++) {
    short8 bkh = *(const short8*)&kph[(nt * 16 + m) * 32 + quad * 8];
    short8 bkl = *(const short8*)&kpl[(nt * 16 + m) * 32 + quad * 8];
    f32x4 p = (f32x4){0.f, 0.f, 0.f, 0.f};
    p = __builtin_amdgcn_mfma_f32_16x16x32_bf16(aqh, bkh, p, 0, 0, 0);
    p = __builtin_amdgcn_mfma_f32_16x16x32_bf16(aqh, bkl, p, 0, 0, 0);
    p = __builtin_amdgcn_mfma_f32_16x16x32_bf16(aql, bkh, p, 0, 0, 0);
    p = __builtin_amdgcn_mfma_f32_16x16x32_bf16(aql, bkl, p, 0, 0, 0);
    accp[nt] = p;
  }

  // ---- epilogue ----
  const float c1 = 0.03608439182435161f;                         // 1/sqrt(768)
  const float hw = log1pf(expf(hwp[h])) * 0.09622504486493764f;  // softplus*sqrt(1/108)
#pragma unroll
  for (int nt = 0; nt < 4; nt++) {
    const int j = j0 + nt * 16 + m;
    const float kp2v = kp2[nt * 16 + m];
    const float mj = mask[j];
#pragma unroll
    for (int r = 0; r < 4; r++) {
      const int i = i0 + ib + quad * 4 + r;
      const float pt = qp2[ib + quad * 4 + r] + kp2v - 2.f * accp[nt][r];
      const float logit = c1 * acc[nt][r]
                        + bbias_t[(size_t)h * 262144 + (size_t)i * 512 + j]
                        - 0.5f * hw * pt
                        + 100000.f * (mask[i] * mj - 1.f);
      attn[((size_t)h * 512 + i) * 512 + j] = logit;
    }
  }
}

// ---------------- row softmax over j (512), in place --------------------------------
__global__ __launch_bounds__(256) void softmax_kernel(float* __restrict__ attn) {
  float* a = attn + (size_t)blockIdx.x * 512;
  const int t = threadIdx.x;
  float v0 = a[t], v1 = a[t + 256];
  __shared__ float redm[4], reds[4];
  float m = fmaxf(v0, v1);
#pragma unroll
  for (int o = 1; o < 64; o <<= 1) m = fmaxf(m, __shfl_xor(m, o));
  if ((t & 63) == 0) redm[t >> 6] = m;
  __syncthreads();
  m = fmaxf(fmaxf(redm[0], redm[1]), fmaxf(redm[2], redm[3]));
  float e0 = expf(v0 - m), e1 = expf(v1 - m);
  float s = e0 + e1;
#pragma unroll
  for (int o = 1; o < 64; o <<= 1) s += __shfl_xor(s, o);
  if ((t & 63) == 0) reds[t >> 6] = s;
  __syncthreads();
  float inv = 1.0f / (reds[0] + reds[1] + reds[2] + reds[3]);
  a[t] = e0 * inv;
  a[t + 256] = e1 * inv;
}

// ---------------- o = a@v, o_pt = a@v_pts (+inverse rigid, norm) ---------------------
__global__ __launch_bounds__(256) void attn_v2(
    const float* __restrict__ attn, const float* __restrict__ vb,
    const float* __restrict__ kvpts, const float* __restrict__ rot,
    const float* __restrict__ trans, float* __restrict__ feats) {
  const int it = blockIdx.x, h = blockIdx.y;   // grid (64, 8)
  const int i0 = it * 8;
  __shared__ float as[8][516];
  __shared__ float opt[8][36];
  const int t = threadIdx.x;
  for (int l = t; l < 8 * 128; l += 256) {
    int i = l >> 7, j4 = (l & 127) * 4;
    *(float4*)&as[i][j4] = *(const float4*)(attn + ((size_t)h * 512 + i0 + i) * 512 + j4);
  }
  __syncthreads();
  const int tx = t & 63, wid = t >> 6;
  const int iA = wid * 2;
  const bool do_p = tx < 36;
  const float* vbase = vb + h * 256 + tx * 4;
  const float* pbase = kvpts + ((size_t)(h * 20 + 8)) * 3 + tx;
  float acc[2][4];
#pragma unroll
  for (int i = 0; i < 2; i++)
#pragma unroll
    for (int j = 0; j < 4; j++) acc[i][j] = 0.f;
  float accp[2] = {0.f, 0.f};

  for (int j = 0; j < 512; j += 4) {
    float4 aA = *(const float4*)&as[iA][j];
    float4 aB = *(const float4*)&as[iA + 1][j];
    const float fA[4] = {aA.x, aA.y, aA.z, aA.w};
    const float fB[4] = {aB.x, aB.y, aB.z, aB.w};
#pragma unroll
    for (int u = 0; u < 4; u++) {
      float4 v4 = *(const float4*)(vbase + (size_t)(j + u) * 2048);
      float vp = do_p ? pbase[(size_t)(j + u) * 480] : 0.f;
      acc[0][0] += fA[u] * v4.x; acc[0][1] += fA[u] * v4.y;
      acc[0][2] += fA[u] * v4.z; acc[0][3] += fA[u] * v4.w;
      acc[1][0] += fB[u] * v4.x; acc[1][1] += fB[u] * v4.y;
      acc[1][2] += fB[u] * v4.z; acc[1][3] += fB[u] * v4.w;
      accp[0] += fA[u] * vp;
      accp[1] += fB[u] * vp;
    }
  }
#pragma unroll
  for (int ii = 0; ii < 2; ii++) {
    int irow = i0 + iA + ii;
    float4 o4 = {acc[ii][0], acc[ii][1], acc[ii][2], acc[ii][3]};
    *(float4*)(feats + (size_t)irow * 2688 + h * 256 + tx * 4) = o4;
    if (do_p) opt[iA + ii][tx] = accp[ii];
  }
  __syncthreads();
  if (t < 96) {
    int i = t / 12, p = t % 12, irow = i0 + i;
    const float* R = rot + irow * 9;
    const float* tr = trans + irow * 3;
    float x = opt[i][p * 3 + 0] - tr[0];
    float y = opt[i][p * 3 + 1] - tr[1];
    float zz = opt[i][p * 3 + 2] - tr[2];
    float o0 = R[0] * x + R[3] * y + R[6] * zz;   // R^T v
    float o1 = R[1] * x + R[4] * y + R[7] * zz;
    float o2 = R[2] * x + R[5] * y + R[8] * zz;
    float nrm = sqrtf(o0 * o0 + o1 * o1 + o2 * o2 + 1e-8f);
    float* fr = feats + (size_t)irow * 2688 + 2048;
    fr[h * 12 + p]       = o0;
    fr[96 + h * 12 + p]  = o1;
    fr[192 + h * 12 + p] = o2;
    fr[288 + h * 12 + p] = nrm;
  }
}

// ---------------- o_pair = a @ pair_z (per query i) ----------------------------------
__global__ __launch_bounds__(256) void o_pair_kernel(
    const float* __restrict__ attn, const float* __restrict__ pairz,
    float* __restrict__ feats) {
  const int i = blockIdx.x;
  __shared__ float as[8][512];
  __shared__ float pzt[64][33];
  const int t = threadIdx.x;
  for (int l = t; l < 8 * 128; l += 256) {
    int hh = l >> 7, j4 = (l & 127) * 4;
    *(float4*)&as[hh][j4] = *(const float4*)(attn + ((size_t)hh * 512 + i) * 512 + j4);
  }
  const int h = t >> 5, d = t & 31;
  float acc = 0.f;
  for (int jt = 0; jt < 512; jt += 64) {
    __syncthreads();
    for (int l = t; l < 64 * 8; l += 256) {
      int j = l >> 3, d4 = (l & 7) * 4;
      float4 p4 = *(const float4*)(pairz + ((size_t)i * 512 + jt + j) * 32 + d4);
      pzt[j][d4 + 0] = p4.x; pzt[j][d4 + 1] = p4.y;
      pzt[j][d4 + 2] = p4.z; pzt[j][d4 + 3] = p4.w;
    }
    __syncthreads();
#pragma unroll
    for (int j = 0; j < 64; j += 4) {
      float4 a4 = *(const float4*)&as[h][jt + j];
      acc += a4.x * pzt[j][d] + a4.y * pzt[j + 1][d] + a4.z * pzt[j + 2][d] + a4.w * pzt[j + 3][d];
    }
  }
  feats[(size_t)i * 2688 + 2432 + h * 32 + d] = acc;
}

// ---------------- final GEMM: out = feats @ wo + bo (split-K=8, atomic) --------------
__global__ __launch_bounds__(256) void out_gemm_kernel(
    const float* __restrict__ feats, const float* __restrict__ wo,
    const float* __restrict__ bo, float* __restrict__ out) {
  __shared__ float As[16][64], Bs[16][64];
  int col0 = blockIdx.x * 64, row0 = blockIdx.y * 64;
  int k0 = blockIdx.z * 336;
  sgemm_tile64(feats, wo, blockIdx.z == 0 ? bo : nullptr, out,
               2688, 384, row0, col0, k0, k0 + 336, true, As, Bs);
}

extern "C" void kernel_launch(void* const* d_in, const int* in_sizes, int n_in,
                              void* d_out, int out_size, void* d_ws, size_t ws_size,
                              hipStream_t stream) {
  const float* s     = (const float*)d_in[0];
  const float* z     = (const float*)d_in[1];
  const float* rot   = (const float*)d_in[2];
  const float* trans = (const float*)d_in[3];
  const float* mask  = (const float*)d_in[4];
  const float* wq    = (const float*)d_in[5];
  const float* bq    = (const float*)d_in[6];
  const float* wkv   = (const float*)d_in[7];
  const float* bkv   = (const float*)d_in[8];
  const float* wqp   = (const float*)d_in[9];
  const float* bqp   = (const float*)d_in[10];
  const float* wkvp  = (const float*)d_in[11];
  const float* bkvp  = (const float*)d_in[12];
  const float* wb    = (const float*)d_in[13];
  const float* bb    = (const float*)d_in[14];
  const float* wz    = (const float*)d_in[15];
  const float* bz    = (const float*)d_in[16];
  const float* hwp   = (const float*)d_in[17];
  const float* wo    = (const float*)d_in[18];
  const float* bo    = (const float*)d_in[19];
  float* out = (float*)d_out;

  float* ws = (float*)d_ws;
  unsigned short* qbh = (unsigned short*)(ws + OFF_QBH);
  unsigned short* kbh = (unsigned short*)(ws + OFF_KBH);
  float* vb      = ws + OFF_VB;
  float* qpraw   = ws + OFF_QPRAW;
  float* kvpraw  = ws + OFF_KVPRAW;
  float* qpts    = ws + OFF_QPTS;
  float* kvpts   = ws + OFF_KVPTS;
  float* bbias_t = ws + OFF_BBIAS;
  float* pairz   = ws + OFF_PAIRZ;
  float* attn    = ws + OFF_ATTN;
  float* feats   = ws + OFF_FEATS;
  unsigned short* wT    = (unsigned short*)(ws + OFF_WCAT);
  unsigned short* wTall = (unsigned short*)(ws + OFF_WTALL);

  prep_wT_all<<<dim3(107, 6), 256, 0, stream>>>(wq, wkv, wqp, wkvp, wTall);
  prep_wT<<<24, 256, 0, stream>>>(wb, wz, wT);
  proj_mfma<<<dim3(107, 8), 256, 0, stream>>>(s, wTall, bq, bkv, bqp, bkvp,
                                              qbh, kbh, vb, qpraw, kvpraw);
  rigid_pts<<<448, 256, 0, stream>>>(qpraw, kvpraw, rot, trans, qpts, kvpts);
  zpass_mfma<<<4096, 256, 0, stream>>>(z, wT, bb, bz, bbias_t, pairz);
  logits_mfma<<<dim3(8, 8, 8), 256, 0, stream>>>(qbh, kbh, qpts, kvpts, bbias_t, mask, hwp, attn);
  softmax_kernel<<<4096, 256, 0, stream>>>(attn);
  attn_v2<<<dim3(64, 8), 256, 0, stream>>>(attn, vb, kvpts, rot, trans, feats);
  o_pair_kernel<<<512, 256, 0, stream>>>(attn, pairz, feats);
  (void)hipMemsetAsync(out, 0, (size_t)out_size * sizeof(float), stream);
  out_gemm_kernel<<<dim3(6, 8, 8), 256, 0, stream>>>(feats, wo, bo, out);
}

// Round 6
// 390.191 us; speedup vs baseline: 1.4030x; 1.1063x over previous
//
#include <hip/hip_runtime.h>

// TranslationIPA: B=1, N=512, CS=384, CZ=128, H=8, C=256, PQ=8, PV=12
// feats layout: [o 2048 | x 96 | y 96 | z 96 | norm 96 | o_pair 256] = 2688

// workspace float offsets
#define OFF_QBH    0          // qbh  us[512*2048] = 524288 fl
#define OFF_KBH    524288     // kbh  us[512*2048]
#define OFF_VB     1048576    // vb   f32[512*2048]
#define OFF_QPRAW  2097152    // f32[512*192]
#define OFF_KVPRAW 2195456    // f32[512*480]
#define OFF_QPTS   2441216    // f32[512*64*3]
#define OFF_KVPTS  2539520    // f32[512*160*3]
#define OFF_BBIAS  2785280    // bbias_tb us[8*262144]  ([h][i*512+j] bf16)
#define OFF_PAIRZT 3833856    // pairzT  us[512*32*512] ([i][d][j] bf16)
#define OFF_ATTNH  8028160    // attn hi us[8*512*512]  ([h][i][j] bf16)
#define OFF_ATTNL  9076736    // attn lo us[8*512*512]
#define OFF_FEATS  10125312   // f32[512*2688]
#define OFF_WCAT   11501568   // us[48*128] z-weights bf16
#define OFF_WTALL  11504640   // us[6848*384] proj weights bf16
#define OFF_VPT    12819456   // vptT us[8*352*512]

typedef __attribute__((ext_vector_type(8))) short short8;   // 8 bf16
typedef __attribute__((ext_vector_type(4))) float f32x4;

__device__ __forceinline__ unsigned short f2bf(float f) {   // RNE f32 -> bf16
  union { float f; unsigned u; } v; v.f = f;
  unsigned u = v.u;
  unsigned r = (u + 0x7fffu + ((u >> 16) & 1u)) >> 16;
  return (unsigned short)r;
}
__device__ __forceinline__ float bf2f(unsigned short h) {
  union { unsigned u; float f; } v; v.u = ((unsigned)h) << 16; return v.f;
}
__device__ __forceinline__ short8 pack8(float4 a, float4 b) {
  short8 r;
  r[0] = (short)f2bf(a.x); r[1] = (short)f2bf(a.y);
  r[2] = (short)f2bf(a.z); r[3] = (short)f2bf(a.w);
  r[4] = (short)f2bf(b.x); r[5] = (short)f2bf(b.y);
  r[6] = (short)f2bf(b.z); r[7] = (short)f2bf(b.w);
  return r;
}

// ---------------- generic 64x64 f32 GEMM tile (out_gemm only) -----------------------
__device__ __forceinline__ void sgemm_tile64(
    const float* __restrict__ A, const float* __restrict__ W,
    const float* bias, float* __restrict__ Cout,
    const int K, const int Ncol, const int row0, const int col0,
    const int k0b, const int k1, const bool atomic,
    float (*As)[64], float (*Bs)[64]) {
  const int t  = threadIdx.x;
  const int tx = t & 15, ty = t >> 4;
  const int am = t >> 2, akq = (t & 3) << 2;
  const int bk = t >> 4, bn = (t & 15) << 2;
  float acc[4][4];
#pragma unroll
  for (int i = 0; i < 4; i++)
#pragma unroll
    for (int j = 0; j < 4; j++) acc[i][j] = 0.f;

  for (int k0 = k0b; k0 < k1; k0 += 16) {
    float4 a4 = *(const float4*)(A + (size_t)(row0 + am) * K + k0 + akq);
    float4 b4 = *(const float4*)(W + (size_t)(k0 + bk) * Ncol + col0 + bn);
    __syncthreads();
    As[akq + 0][am] = a4.x; As[akq + 1][am] = a4.y;
    As[akq + 2][am] = a4.z; As[akq + 3][am] = a4.w;
    *(float4*)&Bs[bk][bn] = b4;
    __syncthreads();
#pragma unroll
    for (int kk = 0; kk < 16; kk++) {
      float4 av = *(const float4*)&As[kk][ty << 2];
      float4 bv = *(const float4*)&Bs[kk][tx << 2];
      acc[0][0] += av.x * bv.x; acc[0][1] += av.x * bv.y; acc[0][2] += av.x * bv.z; acc[0][3] += av.x * bv.w;
      acc[1][0] += av.y * bv.x; acc[1][1] += av.y * bv.y; acc[1][2] += av.y * bv.z; acc[1][3] += av.y * bv.w;
      acc[2][0] += av.z * bv.x; acc[2][1] += av.z * bv.y; acc[2][2] += av.z * bv.z; acc[2][3] += av.z * bv.w;
      acc[3][0] += av.w * bv.x; acc[3][1] += av.w * bv.y; acc[3][2] += av.w * bv.z; acc[3][3] += av.w * bv.w;
    }
  }
#pragma unroll
  for (int i = 0; i < 4; i++) {
    int row = row0 + (ty << 2) + i;
#pragma unroll
    for (int j = 0; j < 4; j++) {
      int col = col0 + (tx << 2) + j;
      float v = acc[i][j] + (bias ? bias[col] : 0.f);
      if (atomic) atomicAdd(&Cout[(size_t)row * Ncol + col], v);
      else Cout[(size_t)row * Ncol + col] = v;
    }
  }
}

// ---------------- prep: transpose all proj weights to bf16 wT_all[6848][384] --------
__global__ __launch_bounds__(256) void prep_wT_all(
    const float* __restrict__ wq, const float* __restrict__ wkv,
    const float* __restrict__ wqp, const float* __restrict__ wkvp,
    unsigned short* __restrict__ wTall) {
  const int ntile = blockIdx.x, kt = blockIdx.y;   // 107 x 6
  const float* src; int Nsrc, nloc0;
  const int ng0 = ntile * 64;
  if (ntile < 32)      { src = wq;   Nsrc = 2048; nloc0 = ng0; }
  else if (ntile < 96) { src = wkv;  Nsrc = 4096; nloc0 = ng0 - 2048; }
  else if (ntile < 99) { src = wqp;  Nsrc = 192;  nloc0 = ng0 - 6144; }
  else                 { src = wkvp; Nsrc = 480;  nloc0 = ng0 - 6336; }
  __shared__ float tile[64][65];
  const int t = threadIdx.x;
  const int r = t >> 2, cs = (t & 3) * 16;
#pragma unroll
  for (int i = 0; i < 16; i += 4) {
    int n = nloc0 + cs + i;
    float4 v;
    if (n + 3 < Nsrc) v = *(const float4*)(src + (size_t)(kt * 64 + r) * Nsrc + n);
    else {
      v.x = (n + 0 < Nsrc) ? src[(size_t)(kt * 64 + r) * Nsrc + n + 0] : 0.f;
      v.y = (n + 1 < Nsrc) ? src[(size_t)(kt * 64 + r) * Nsrc + n + 1] : 0.f;
      v.z = (n + 2 < Nsrc) ? src[(size_t)(kt * 64 + r) * Nsrc + n + 2] : 0.f;
      v.w = (n + 3 < Nsrc) ? src[(size_t)(kt * 64 + r) * Nsrc + n + 3] : 0.f;
    }
    tile[r][cs + i + 0] = v.x; tile[r][cs + i + 1] = v.y;
    tile[r][cs + i + 2] = v.z; tile[r][cs + i + 3] = v.w;
  }
  __syncthreads();
  const int nr = t >> 2, ks = (t & 3) * 16;
  unsigned short ov[16];
#pragma unroll
  for (int i = 0; i < 16; i++) ov[i] = f2bf(tile[ks + i][nr]);
  unsigned short* dst = wTall + (size_t)(ng0 + nr) * 384 + kt * 64 + ks;
  *(uint4*)(dst) = *(const uint4*)&ov[0];
  *(uint4*)(dst + 8) = *(const uint4*)&ov[8];
}

// ---------------- proj via MFMA (unchanged from R5) ---------------------------------
__global__ __launch_bounds__(256) void proj_mfma(
    const float* __restrict__ s, const unsigned short* __restrict__ wTall,
    const float* __restrict__ bq, const float* __restrict__ bkv,
    const float* __restrict__ bqp, const float* __restrict__ bkvp,
    unsigned short* __restrict__ qbh, unsigned short* __restrict__ kbh,
    float* __restrict__ vb, float* __restrict__ qpraw, float* __restrict__ kvpraw) {
  const int bx = blockIdx.x, row0 = blockIdx.y * 64;
  const int lane = threadIdx.x & 63, wv = threadIdx.x >> 6;
  const int quad = lane >> 4, m = lane & 15;
  const int n0 = bx * 64;
  const float* srow = s + (size_t)(row0 + wv * 16 + m) * 384;
  f32x4 acc[4];
#pragma unroll
  for (int nt = 0; nt < 4; nt++) acc[nt] = (f32x4){0.f, 0.f, 0.f, 0.f};

#pragma unroll
  for (int ksx = 0; ksx < 12; ksx++) {
    const int c0 = ksx * 32 + quad * 8;
    float4 a0 = *(const float4*)(srow + c0);
    float4 a1 = *(const float4*)(srow + c0 + 4);
    short8 af = pack8(a0, a1);
#pragma unroll
    for (int nt = 0; nt < 4; nt++) {
      short8 bf = *(const short8*)(wTall + (size_t)(n0 + nt * 16 + m) * 384 + c0);
      acc[nt] = __builtin_amdgcn_mfma_f32_16x16x32_bf16(af, bf, acc[nt], 0, 0, 0);
    }
  }

  const int rbase = row0 + wv * 16 + quad * 4;
#pragma unroll
  for (int nt = 0; nt < 4; nt++) {
    const int col = n0 + nt * 16 + m;
    if (n0 < 2048) {
      const float bias = bq[col];
#pragma unroll
      for (int r = 0; r < 4; r++)
        qbh[(size_t)(rbase + r) * 2048 + col] = f2bf(acc[nt][r] + bias);
    } else if (n0 < 6144) {
      const int ckv = col - 2048;
      const float bias = bkv[ckv];
      const int hh = ckv >> 9, c = ckv & 511;
      if (c < 256) {
#pragma unroll
        for (int r = 0; r < 4; r++)
          kbh[(size_t)(rbase + r) * 2048 + hh * 256 + c] = f2bf(acc[nt][r] + bias);
      } else {
#pragma unroll
        for (int r = 0; r < 4; r++)
          vb[(size_t)(rbase + r) * 2048 + hh * 256 + (c - 256)] = acc[nt][r] + bias;
      }
    } else if (n0 < 6336) {
      const int cq = col - 6144;
      const float bias = bqp[cq];
#pragma unroll
      for (int r = 0; r < 4; r++)
        qpraw[(size_t)(rbase + r) * 192 + cq] = acc[nt][r] + bias;
    } else {
      const int ck = col - 6336;
      if (ck < 480) {
        const float bias = bkvp[ck];
#pragma unroll
        for (int r = 0; r < 4; r++)
          kvpraw[(size_t)(rbase + r) * 480 + ck] = acc[nt][r] + bias;
      }
    }
  }
}

// ---------------- rigid transform of point projections ------------------------------
__global__ __launch_bounds__(256) void rigid_pts(
    const float* __restrict__ qpraw, const float* __restrict__ kvpraw,
    const float* __restrict__ rot, const float* __restrict__ trans,
    float* __restrict__ qpts, float* __restrict__ kvpts) {
  int gid = blockIdx.x * 256 + threadIdx.x;
  int n = gid / 224, r = gid % 224;
  const float* R  = rot + n * 9;
  const float* tr = trans + n * 3;
  float px, py, pz; float* dst;
  if (r < 64) {
    const float* src = qpraw + (size_t)n * 192;
    px = src[r]; py = src[64 + r]; pz = src[128 + r];
    dst = qpts + ((size_t)n * 64 + r) * 3;
  } else {
    int p = r - 64;
    const float* src = kvpraw + (size_t)n * 480;
    px = src[p]; py = src[160 + p]; pz = src[320 + p];
    dst = kvpts + ((size_t)n * 160 + p) * 3;
  }
  dst[0] = R[0] * px + R[1] * py + R[2] * pz + tr[0];
  dst[1] = R[3] * px + R[4] * py + R[5] * pz + tr[1];
  dst[2] = R[6] * px + R[7] * py + R[8] * pz + tr[2];
}

// ---------------- pack z-weights transposed bf16 ------------------------------------
__global__ __launch_bounds__(256) void prep_wT(
    const float* __restrict__ wb, const float* __restrict__ wz,
    unsigned short* __restrict__ wT) {
  int l = blockIdx.x * 256 + threadIdx.x;  // 48*128 = 6144
  if (l < 6144) {
    int n = l >> 7, k = l & 127;
    float v = (n < 8) ? wb[k * 8 + n] * 0.5773502691896258f
                      : (n < 40 ? wz[k * 32 + (n - 8)] : 0.f);
    wT[l] = f2bf(v);
  }
}

// ---------------- z-pass: MFMA + LDS repack -> coalesced bf16 outputs ---------------
// bbias_tb[h][i*512+j] bf16 (incl sqrt(1/3)*(..+bb)); pairzT[i][d][j] bf16
__global__ __launch_bounds__(256) void zpass_mfma(
    const float* __restrict__ z, const unsigned short* __restrict__ wT,
    const float* __restrict__ bb, const float* __restrict__ bz,
    unsigned short* __restrict__ bbias_tb, unsigned short* __restrict__ pairzT) {
  __shared__ __align__(16) unsigned short lb[4][8][16];
  __shared__ __align__(16) unsigned short lp[4][32][16];
  const int lane = threadIdx.x & 63;
  const int wave = threadIdx.x >> 6;
  const int quad = lane >> 4, m = lane & 15;
  const int tile = blockIdx.x * 4 + wave;
  const int row0 = tile * 16;

  short8 bf[3][4];
#pragma unroll
  for (int nt = 0; nt < 3; nt++)
#pragma unroll
    for (int s = 0; s < 4; s++)
      bf[nt][s] = *(const short8*)(wT + (size_t)(nt * 16 + m) * 128 + s * 32 + quad * 8);

  float bias[3];
#pragma unroll
  for (int nt = 0; nt < 3; nt++) {
    int c = nt * 16 + m;
    bias[nt] = (c < 8) ? 0.5773502691896258f * bb[c] : (c < 40 ? bz[c - 8] : 0.f);
  }

  f32x4 acc[3];
#pragma unroll
  for (int nt = 0; nt < 3; nt++) acc[nt] = (f32x4){0.f, 0.f, 0.f, 0.f};

  const float* zr = z + (size_t)(row0 + m) * 128 + quad * 8;
#pragma unroll
  for (int s = 0; s < 4; s++) {
    float4 a0 = *(const float4*)(zr + s * 32);
    float4 a1 = *(const float4*)(zr + s * 32 + 4);
    short8 af = pack8(a0, a1);
#pragma unroll
    for (int nt = 0; nt < 3; nt++)
      acc[nt] = __builtin_amdgcn_mfma_f32_16x16x32_bf16(af, bf[nt][s], acc[nt], 0, 0, 0);
  }

  // scatter tile into wave-local LDS (c-major), then coalesced 16B stores
#pragma unroll
  for (int nt = 0; nt < 3; nt++) {
    const int c = nt * 16 + m;
#pragma unroll
    for (int r = 0; r < 4; r++) {
      const float v = acc[nt][r] + bias[nt];
      const int jl = quad * 4 + r;
      if (c < 8)       lb[wave][c][jl] = f2bf(v);
      else if (c < 40) lp[wave][c - 8][jl] = f2bf(v);
    }
  }
  const int i = row0 >> 9, j0 = row0 & 511;
  if (lane < 16) {
    int c = lane >> 1, half = lane & 1;
    uint4 val = *(const uint4*)&lb[wave][c][half * 8];
    *(uint4*)(bbias_tb + (size_t)c * 262144 + row0 + half * 8) = val;
  }
  {
    int d = lane >> 1, half = lane & 1;
    uint4 val = *(const uint4*)&lp[wave][d][half * 8];
    *(uint4*)(pairzT + ((size_t)i * 32 + d) * 512 + j0 + half * 8) = val;
  }
}

// ---------------- vptT prep: [h][n][j] bf16, n: 0-255 v, 256-303 ptsHi, 304-351 ptsLo
__global__ __launch_bounds__(256) void vpt_prep(
    const float* __restrict__ vb, const float* __restrict__ kvpts,
    unsigned short* __restrict__ vptT) {
  const int jt = blockIdx.x, h = blockIdx.y, part = blockIdx.z;
  const int j0 = jt * 64, t = threadIdx.x;
  if (part < 4) {
    __shared__ float tile[64][65];
    const int c0 = part * 64;
    const int r = t >> 2, cs = (t & 3) * 16;
#pragma unroll
    for (int ii = 0; ii < 16; ii += 4) {
      float4 v = *(const float4*)(vb + (size_t)(j0 + r) * 2048 + h * 256 + c0 + cs + ii);
      tile[r][cs + ii + 0] = v.x; tile[r][cs + ii + 1] = v.y;
      tile[r][cs + ii + 2] = v.z; tile[r][cs + ii + 3] = v.w;
    }
    __syncthreads();
    const int cl = t >> 2, js = (t & 3) * 16;
    unsigned short ov[16];
#pragma unroll
    for (int x = 0; x < 16; x++) ov[x] = f2bf(tile[js + x][cl]);
    unsigned short* dst = vptT + ((size_t)h * 352 + c0 + cl) * 512 + j0 + js;
    *(uint4*)dst = *(const uint4*)&ov[0];
    *(uint4*)(dst + 8) = *(const uint4*)&ov[8];
  } else {
    __shared__ float lds[64][37];
    for (int l = t; l < 64 * 36; l += 256) {
      int jl = l / 36, w = l % 36;
      lds[jl][w] = kvpts[((size_t)(j0 + jl) * 160 + h * 20 + 8) * 3 + w];
    }
    __syncthreads();
#pragma unroll
    for (int step = 0; step < 3; step++) {
      int chunk = t + 256 * step;          // < 768 = 96 rows x 8 chunks
      int row = chunk >> 3, js = (chunk & 7) * 8;
      unsigned short ov[8];
#pragma unroll
      for (int x = 0; x < 8; x++) {
        int w = (row < 48) ? row : row - 48;
        float f = (w < 36) ? lds[js + x][w] : 0.f;
        unsigned short hi = f2bf(f);
        ov[x] = (row < 48) ? hi : f2bf(f - bf2f(hi));
      }
      *(uint4*)(vptT + ((size_t)h * 352 + 256 + row) * 512 + j0 + js) = *(const uint4*)&ov[0];
    }
  }
}

// ---------------- fused logits + softmax -> attn bf16 hi/lo --------------------------
// grid (32, 8): block owns 16 i-rows x 512 j for head h; wave w owns j in [w*128, w*128+128)
__global__ __launch_bounds__(256) void logits_softmax(
    const unsigned short* __restrict__ qbh, const unsigned short* __restrict__ kbh,
    const float* __restrict__ qpts, const float* __restrict__ kvpts,
    const unsigned short* __restrict__ bbias_tb, const float* __restrict__ mask,
    const float* __restrict__ hwp,
    unsigned short* __restrict__ attnh, unsigned short* __restrict__ attnl) {
  const int it = blockIdx.x, h = blockIdx.y;
  const int i0 = it * 16;
  __shared__ __align__(16) unsigned short kph[512][32], kpl[512][32];
  __shared__ __align__(16) unsigned short qph[16][32], qpl[16][32];
  __shared__ float kp2[512], qp2[16];
  __shared__ float redm[16][4], reds[16][4];
  __shared__ __align__(16) unsigned short sth[4][16][128], stl[4][16][128];
  const int t = threadIdx.x;

  // stage k-points hi/lo + |k|^2 (2 rows/thread), q-points (t<16)
#pragma unroll
  for (int rr = 0; rr < 2; rr++) {
    const int j = t * 2 + rr;
    const float* src = kvpts + ((size_t)j * 160 + h * 20) * 3;
    float s2 = 0.f;
#pragma unroll
    for (int w = 0; w < 24; w++) {
      float x = src[w];
      unsigned short hi = f2bf(x);
      kph[j][w] = hi; kpl[j][w] = f2bf(x - bf2f(hi));
      s2 += x * x;
    }
#pragma unroll
    for (int w = 24; w < 32; w++) { kph[j][w] = 0; kpl[j][w] = 0; }
    kp2[j] = s2;
  }
  if (t < 16) {
    const float* src = qpts + ((size_t)(i0 + t) * 64 + h * 8) * 3;
    float s2 = 0.f;
#pragma unroll
    for (int w = 0; w < 24; w++) {
      float x = src[w];
      unsigned short hi = f2bf(x);
      qph[t][w] = hi; qpl[t][w] = f2bf(x - bf2f(hi));
      s2 += x * x;
    }
#pragma unroll
    for (int w = 24; w < 32; w++) { qph[t][w] = 0; qpl[t][w] = 0; }
    qp2[t] = s2;
  }
  __syncthreads();

  const int lane = t & 63, wv = t >> 6;
  const int quad = lane >> 4, m = lane & 15;
  const int jw0 = wv * 128;

  // QK^T
  f32x4 acc[8];
#pragma unroll
  for (int nt = 0; nt < 8; nt++) acc[nt] = (f32x4){0.f, 0.f, 0.f, 0.f};
  const unsigned short* qrow = qbh + (size_t)(i0 + m) * 2048 + h * 256;
#pragma unroll
  for (int s = 0; s < 8; s++) {
    short8 af = *(const short8*)(qrow + s * 32 + quad * 8);
#pragma unroll
    for (int nt = 0; nt < 8; nt++) {
      short8 bfr = *(const short8*)(kbh + (size_t)(jw0 + nt * 16 + m) * 2048 + h * 256 + s * 32 + quad * 8);
      acc[nt] = __builtin_amdgcn_mfma_f32_16x16x32_bf16(af, bfr, acc[nt], 0, 0, 0);
    }
  }

  // point cross-term (hi/lo split)
  short8 aqh = *(const short8*)&qph[m][quad * 8];
  short8 aql = *(const short8*)&qpl[m][quad * 8];
  f32x4 accp[8];
#pragma unroll
  for (int nt = 0; nt < 8; nt++) {
    short8 bkh = *(const short8*)&kph[jw0 + nt * 16 + m][quad * 8];
    short8 bkl = *(const short8*)&kpl[jw0 + nt * 16 + m][quad * 8];
    f32x4 p = (f32x4){0.f, 0.f, 0.f, 0.f};
    p = __builtin_amdgcn_mfma_f32_16x16x32_bf16(aqh, bkh, p, 0, 0, 0);
    p = __builtin_amdgcn_mfma_f32_16x16x32_bf16(aqh, bkl, p, 0, 0, 0);
    p = __builtin_amdgcn_mfma_f32_16x16x32_bf16(aql, bkh, p, 0, 0, 0);
    accp[nt] = p;
  }

  // logits
  const float c1 = 0.03608439182435161f;
  const float hw = log1pf(expf(hwp[h])) * 0.09622504486493764f;
  float lg[8][4];
  float rmax[4] = {-1e30f, -1e30f, -1e30f, -1e30f};
#pragma unroll
  for (int nt = 0; nt < 8; nt++) {
    const int j = jw0 + nt * 16 + m;
    const float kp2v = kp2[j];
    const float mj = mask[j];
#pragma unroll
    for (int r = 0; r < 4; r++) {
      const int il = quad * 4 + r;
      const float pt = qp2[il] + kp2v - 2.f * accp[nt][r];
      float v = c1 * acc[nt][r]
              + bf2f(bbias_tb[(size_t)h * 262144 + (size_t)(i0 + il) * 512 + j])
              - 0.5f * hw * pt
              + 100000.f * (mask[i0 + il] * mj - 1.f);
      lg[nt][r] = v;
      rmax[r] = fmaxf(rmax[r], v);
    }
  }
  // row max across m lanes, then across waves
#pragma unroll
  for (int r = 0; r < 4; r++) {
#pragma unroll
    for (int off = 1; off < 16; off <<= 1) rmax[r] = fmaxf(rmax[r], __shfl_xor(rmax[r], off));
  }
  if (m == 0) {
#pragma unroll
    for (int r = 0; r < 4; r++) redm[quad * 4 + r][wv] = rmax[r];
  }
  __syncthreads();
  float rowm[4], rsum[4];
#pragma unroll
  for (int r = 0; r < 4; r++) {
    const int il = quad * 4 + r;
    rowm[r] = fmaxf(fmaxf(redm[il][0], redm[il][1]), fmaxf(redm[il][2], redm[il][3]));
    rsum[r] = 0.f;
  }
#pragma unroll
  for (int nt = 0; nt < 8; nt++)
#pragma unroll
    for (int r = 0; r < 4; r++) {
      float e = __expf(lg[nt][r] - rowm[r]);
      lg[nt][r] = e;
      rsum[r] += e;
    }
#pragma unroll
  for (int r = 0; r < 4; r++) {
#pragma unroll
    for (int off = 1; off < 16; off <<= 1) rsum[r] += __shfl_xor(rsum[r], off);
  }
  if (m == 0) {
#pragma unroll
    for (int r = 0; r < 4; r++) reds[quad * 4 + r][wv] = rsum[r];
  }
  __syncthreads();
  float inv[4];
#pragma unroll
  for (int r = 0; r < 4; r++) {
    const int il = quad * 4 + r;
    inv[r] = 1.f / (reds[il][0] + reds[il][1] + reds[il][2] + reds[il][3]);
  }
  // normalized weights -> bf16 hi/lo via wave-local LDS staging, coalesced stores
#pragma unroll
  for (int nt = 0; nt < 8; nt++)
#pragma unroll
    for (int r = 0; r < 4; r++) {
      const int il = quad * 4 + r;
      float a = lg[nt][r] * inv[r];
      unsigned short hi = f2bf(a);
      sth[wv][il][nt * 16 + m] = hi;
      stl[wv][il][nt * 16 + m] = f2bf(a - bf2f(hi));
    }
#pragma unroll
  for (int step = 0; step < 4; step++) {
    const int idx = lane + 64 * step;        // 0..255 = 16 rows x 16 segs
    const int il = idx >> 4, seg = idx & 15;
    uint4 vh = *(const uint4*)&sth[wv][il][seg * 8];
    uint4 vl = *(const uint4*)&stl[wv][il][seg * 8];
    const size_t off = ((size_t)h * 512 + i0 + il) * 512 + jw0 + seg * 8;
    *(uint4*)(attnh + off) = vh;
    *(uint4*)(attnl + off) = vl;
  }
}

// ---------------- attn_v3: o = a@v, o_pt = a@v_pts via MFMA --------------------------
// grid (32, 8): block = 16 i-rows; waves split the 22 n-tiles of vptT
__global__ __launch_bounds__(256) void attn_v3(
    const unsigned short* __restrict__ attnh, const unsigned short* __restrict__ attnl,
    const unsigned short* __restrict__ vptT,
    const float* __restrict__ rot, const float* __restrict__ trans,
    float* __restrict__ feats) {
  const int it = blockIdx.x, h = blockIdx.y;
  const int i0 = it * 16;
  __shared__ float lds_h[16][48], lds_l[16][48];
  const int t = threadIdx.x;
  const int lane = t & 63, wv = t >> 6;
  const int quad = lane >> 4, m = lane & 15;
  const int nt0 = wv * 6;
  const int ncnt = (wv == 3) ? 4 : 6;

  f32x4 acc[6];
#pragma unroll
  for (int k = 0; k < 6; k++) acc[k] = (f32x4){0.f, 0.f, 0.f, 0.f};

  const size_t arow = ((size_t)h * 512 + i0 + m) * 512;
  const unsigned short* vbase = vptT + (size_t)h * 352 * 512;
#pragma unroll
  for (int s = 0; s < 16; s++) {
    const int ko = s * 32 + quad * 8;
    short8 ah = *(const short8*)(attnh + arow + ko);
    short8 al = *(const short8*)(attnl + arow + ko);
#pragma unroll
    for (int k = 0; k < 6; k++) {
      if (k < ncnt) {
        const int nt = nt0 + k;
        short8 bfr = *(const short8*)(vbase + (size_t)(nt * 16 + m) * 512 + ko);
        acc[k] = __builtin_amdgcn_mfma_f32_16x16x32_bf16(ah, bfr, acc[k], 0, 0, 0);
        if (nt >= 16 && nt < 19)   // pts-hi tiles: add a-lo contribution
          acc[k] = __builtin_amdgcn_mfma_f32_16x16x32_bf16(al, bfr, acc[k], 0, 0, 0);
      }
    }
  }

#pragma unroll
  for (int k = 0; k < 6; k++) {
    if (k < ncnt) {
      const int nt = nt0 + k;
      if (nt < 16) {
#pragma unroll
        for (int r = 0; r < 4; r++)
          feats[(size_t)(i0 + quad * 4 + r) * 2688 + h * 256 + nt * 16 + m] = acc[k][r];
      } else if (nt < 19) {
        const int w = (nt - 16) * 16 + m;
#pragma unroll
        for (int r = 0; r < 4; r++) if (w < 36) lds_h[quad * 4 + r][w] = acc[k][r];
      } else {
        const int w = (nt - 19) * 16 + m;
#pragma unroll
        for (int r = 0; r < 4; r++) if (w < 36) lds_l[quad * 4 + r][w] = acc[k][r];
      }
    }
  }
  __syncthreads();
  if (t < 192) {
    const int il = t / 12, p = t % 12, irow = i0 + il;
    const float* R = rot + irow * 9;
    const float* tr = trans + irow * 3;
    float x  = lds_h[il][p * 3 + 0] + lds_l[il][p * 3 + 0] - tr[0];
    float y  = lds_h[il][p * 3 + 1] + lds_l[il][p * 3 + 1] - tr[1];
    float zz = lds_h[il][p * 3 + 2] + lds_l[il][p * 3 + 2] - tr[2];
    float o0 = R[0] * x + R[3] * y + R[6] * zz;   // R^T v
    float o1 = R[1] * x + R[4] * y + R[7] * zz;
    float o2 = R[2] * x + R[5] * y + R[8] * zz;
    float nrm = sqrtf(o0 * o0 + o1 * o1 + o2 * o2 + 1e-8f);
    float* fr = feats + (size_t)irow * 2688 + 2048;
    fr[h * 12 + p]       = o0;
    fr[96 + h * 12 + p]  = o1;
    fr[192 + h * 12 + p] = o2;
    fr[288 + h * 12 + p] = nrm;
  }
}

// ---------------- o_pair via MFMA: per-i [8h x 512j] @ [512j x 32d] ------------------
__global__ __launch_bounds__(256) void o_pair_mfma(
    const unsigned short* __restrict__ attnh, const unsigned short* __restrict__ pairzT,
    float* __restrict__ feats) {
  const int lane = threadIdx.x & 63, wv = threadIdx.x >> 6;
  const int quad = lane >> 4, m = lane & 15;
  const int i = blockIdx.x * 4 + wv;          // grid 128
  f32x4 acc[2];
  acc[0] = (f32x4){0.f, 0.f, 0.f, 0.f};
  acc[1] = (f32x4){0.f, 0.f, 0.f, 0.f};
#pragma unroll
  for (int s = 0; s < 16; s++) {
    const int ko = s * 32 + quad * 8;
    short8 af = *(const short8*)(attnh + (size_t)(m & 7) * 262144 + (size_t)i * 512 + ko);
#pragma unroll
    for (int nt = 0; nt < 2; nt++) {
      short8 bfr = *(const short8*)(pairzT + ((size_t)i * 32 + nt * 16 + m) * 512 + ko);
      acc[nt] = __builtin_amdgcn_mfma_f32_16x16x32_bf16(af, bfr, acc[nt], 0, 0, 0);
    }
  }
  if (quad < 2) {
#pragma unroll
    for (int nt = 0; nt < 2; nt++)
#pragma unroll
      for (int r = 0; r < 4; r++) {
        const int hh = quad * 4 + r, d = nt * 16 + m;
        feats[(size_t)i * 2688 + 2432 + hh * 32 + d] = acc[nt][r];
      }
  }
}

// ---------------- final GEMM: out = feats @ wo + bo (split-K=8, atomic) --------------
__global__ __launch_bounds__(256) void out_gemm_kernel(
    const float* __restrict__ feats, const float* __restrict__ wo,
    const float* __restrict__ bo, float* __restrict__ out) {
  __shared__ float As[16][64], Bs[16][64];
  int col0 = blockIdx.x * 64, row0 = blockIdx.y * 64;
  int k0 = blockIdx.z * 336;
  sgemm_tile64(feats, wo, blockIdx.z == 0 ? bo : nullptr, out,
               2688, 384, row0, col0, k0, k0 + 336, true, As, Bs);
}

extern "C" void kernel_launch(void* const* d_in, const int* in_sizes, int n_in,
                              void* d_out, int out_size, void* d_ws, size_t ws_size,
                              hipStream_t stream) {
  const float* s     = (const float*)d_in[0];
  const float* z     = (const float*)d_in[1];
  const float* rot   = (const float*)d_in[2];
  const float* trans = (const float*)d_in[3];
  const float* mask  = (const float*)d_in[4];
  const float* wq    = (const float*)d_in[5];
  const float* bq    = (const float*)d_in[6];
  const float* wkv   = (const float*)d_in[7];
  const float* bkv   = (const float*)d_in[8];
  const float* wqp   = (const float*)d_in[9];
  const float* bqp   = (const float*)d_in[10];
  const float* wkvp  = (const float*)d_in[11];
  const float* bkvp  = (const float*)d_in[12];
  const float* wb    = (const float*)d_in[13];
  const float* bb    = (const float*)d_in[14];
  const float* wz    = (const float*)d_in[15];
  const float* bz    = (const float*)d_in[16];
  const float* hwp   = (const float*)d_in[17];
  const float* wo    = (const float*)d_in[18];
  const float* bo    = (const float*)d_in[19];
  float* out = (float*)d_out;

  float* ws = (float*)d_ws;
  unsigned short* qbh   = (unsigned short*)(ws + OFF_QBH);
  unsigned short* kbh   = (unsigned short*)(ws + OFF_KBH);
  float* vb      = ws + OFF_VB;
  float* qpraw   = ws + OFF_QPRAW;
  float* kvpraw  = ws + OFF_KVPRAW;
  float* qpts    = ws + OFF_QPTS;
  float* kvpts   = ws + OFF_KVPTS;
  unsigned short* bbias_tb = (unsigned short*)(ws + OFF_BBIAS);
  unsigned short* pairzT   = (unsigned short*)(ws + OFF_PAIRZT);
  unsigned short* attnh    = (unsigned short*)(ws + OFF_ATTNH);
  unsigned short* attnl    = (unsigned short*)(ws + OFF_ATTNL);
  float* feats   = ws + OFF_FEATS;
  unsigned short* wT    = (unsigned short*)(ws + OFF_WCAT);
  unsigned short* wTall = (unsigned short*)(ws + OFF_WTALL);
  unsigned short* vptT  = (unsigned short*)(ws + OFF_VPT);

  prep_wT_all<<<dim3(107, 6), 256, 0, stream>>>(wq, wkv, wqp, wkvp, wTall);
  prep_wT<<<24, 256, 0, stream>>>(wb, wz, wT);
  proj_mfma<<<dim3(107, 8), 256, 0, stream>>>(s, wTall, bq, bkv, bqp, bkvp,
                                              qbh, kbh, vb, qpraw, kvpraw);
  rigid_pts<<<448, 256, 0, stream>>>(qpraw, kvpraw, rot, trans, qpts, kvpts);
  zpass_mfma<<<4096, 256, 0, stream>>>(z, wT, bb, bz, bbias_tb, pairzT);
  vpt_prep<<<dim3(8, 8, 5), 256, 0, stream>>>(vb, kvpts, vptT);
  logits_softmax<<<dim3(32, 8), 256, 0, stream>>>(qbh, kbh, qpts, kvpts, bbias_tb,
                                                  mask, hwp, attnh, attnl);
  attn_v3<<<dim3(32, 8), 256, 0, stream>>>(attnh, attnl, vptT, rot, trans, feats);
  o_pair_mfma<<<128, 256, 0, stream>>>(attnh, pairzT, feats);
  (void)hipMemsetAsync(out, 0, (size_t)out_size * sizeof(float), stream);
  out_gemm_kernel<<<dim3(6, 8, 8), 256, 0, stream>>>(feats, wo, bo, out);
}

// Round 7
// 368.627 us; speedup vs baseline: 1.4850x; 1.0585x over previous
//
#include <hip/hip_runtime.h>

// TranslationIPA: B=1, N=512, CS=384, CZ=128, H=8, C=256, PQ=8, PV=12
// feats layout: [o 2048 | x 96 | y 96 | z 96 | norm 96 | o_pair 256] = 2688

// workspace float offsets
#define OFF_QBH    0          // qbh  us[512*2048]
#define OFF_KBH    524288     // kbh  us[512*2048]
#define OFF_VB     1048576    // vb   f32[512*2048]
#define OFF_QPRAW  2097152    // f32[512*192]
#define OFF_KVPRAW 2195456    // f32[512*480]
#define OFF_QPTS   2441216    // f32[512*64*3]
#define OFF_KVPTS  2539520    // f32[512*160*3]
#define OFF_BBIAS  2785280    // us[8*262144]  ([h][i*512+j] bf16)
#define OFF_PAIRZT 3833856    // us[512*32*512] ([i][d][j] bf16)
#define OFF_ATTNH  8028160    // us[8*512*512] ([h][i][j] bf16)
#define OFF_FEATSB 9076736    // us[512*2688] bf16
#define OFF_WCAT   9764864    // us[48*128]
#define OFF_WTALL  9767936    // us[6848*384]
#define OFF_VPT    11082752   // us[8*352*512]
#define OFF_WOT    11803648   // us[384*2688]
#define OFF_QPTH   12319744   // us[8*512*32]
#define OFF_QPTL   12385280   // us[8*512*32]
#define OFF_KPTH   12450816   // us[8*512*32]
#define OFF_KPTL   12516352   // us[8*512*32]
#define OFF_QP2    12581888   // f32[8*512]
#define OFF_KP2    12585984   // f32[8*512]

typedef __attribute__((ext_vector_type(8))) short short8;   // 8 bf16
typedef __attribute__((ext_vector_type(4))) float f32x4;

__device__ __forceinline__ unsigned short f2bf(float f) {   // RNE f32 -> bf16
  union { float f; unsigned u; } v; v.f = f;
  unsigned u = v.u;
  unsigned r = (u + 0x7fffu + ((u >> 16) & 1u)) >> 16;
  return (unsigned short)r;
}
__device__ __forceinline__ float bf2f(unsigned short h) {
  union { unsigned u; float f; } v; v.u = ((unsigned)h) << 16; return v.f;
}
__device__ __forceinline__ short8 pack8(float4 a, float4 b) {
  short8 r;
  r[0] = (short)f2bf(a.x); r[1] = (short)f2bf(a.y);
  r[2] = (short)f2bf(a.z); r[3] = (short)f2bf(a.w);
  r[4] = (short)f2bf(b.x); r[5] = (short)f2bf(b.y);
  r[6] = (short)f2bf(b.z); r[7] = (short)f2bf(b.w);
  return r;
}

// ---------------- prep: transpose all proj weights to bf16 wT_all[6848][384] --------
__global__ __launch_bounds__(256) void prep_wT_all(
    const float* __restrict__ wq, const float* __restrict__ wkv,
    const float* __restrict__ wqp, const float* __restrict__ wkvp,
    unsigned short* __restrict__ wTall) {
  const int ntile = blockIdx.x, kt = blockIdx.y;   // 107 x 6
  const float* src; int Nsrc, nloc0;
  const int ng0 = ntile * 64;
  if (ntile < 32)      { src = wq;   Nsrc = 2048; nloc0 = ng0; }
  else if (ntile < 96) { src = wkv;  Nsrc = 4096; nloc0 = ng0 - 2048; }
  else if (ntile < 99) { src = wqp;  Nsrc = 192;  nloc0 = ng0 - 6144; }
  else                 { src = wkvp; Nsrc = 480;  nloc0 = ng0 - 6336; }
  __shared__ float tile[64][65];
  const int t = threadIdx.x;
  const int r = t >> 2, cs = (t & 3) * 16;
#pragma unroll
  for (int i = 0; i < 16; i += 4) {
    int n = nloc0 + cs + i;
    float4 v;
    if (n + 3 < Nsrc) v = *(const float4*)(src + (size_t)(kt * 64 + r) * Nsrc + n);
    else {
      v.x = (n + 0 < Nsrc) ? src[(size_t)(kt * 64 + r) * Nsrc + n + 0] : 0.f;
      v.y = (n + 1 < Nsrc) ? src[(size_t)(kt * 64 + r) * Nsrc + n + 1] : 0.f;
      v.z = (n + 2 < Nsrc) ? src[(size_t)(kt * 64 + r) * Nsrc + n + 2] : 0.f;
      v.w = (n + 3 < Nsrc) ? src[(size_t)(kt * 64 + r) * Nsrc + n + 3] : 0.f;
    }
    tile[r][cs + i + 0] = v.x; tile[r][cs + i + 1] = v.y;
    tile[r][cs + i + 2] = v.z; tile[r][cs + i + 3] = v.w;
  }
  __syncthreads();
  const int nr = t >> 2, ks = (t & 3) * 16;
  unsigned short ov[16];
#pragma unroll
  for (int i = 0; i < 16; i++) ov[i] = f2bf(tile[ks + i][nr]);
  unsigned short* dst = wTall + (size_t)(ng0 + nr) * 384 + kt * 64 + ks;
  *(uint4*)(dst) = *(const uint4*)&ov[0];
  *(uint4*)(dst + 8) = *(const uint4*)&ov[8];
}

// ---------------- prep: transpose wo[2688][384] -> woT[384][2688] bf16 ---------------
__global__ __launch_bounds__(256) void prep_woT(
    const float* __restrict__ wo, unsigned short* __restrict__ woT) {
  const int kt = blockIdx.x, ntile = blockIdx.y;   // 42 x 6
  __shared__ float tile[64][65];
  const int t = threadIdx.x;
  const int r = t >> 2, cs = (t & 3) * 16;
#pragma unroll
  for (int i = 0; i < 16; i += 4) {
    float4 v = *(const float4*)(wo + (size_t)(kt * 64 + r) * 384 + ntile * 64 + cs + i);
    tile[r][cs + i + 0] = v.x; tile[r][cs + i + 1] = v.y;
    tile[r][cs + i + 2] = v.z; tile[r][cs + i + 3] = v.w;
  }
  __syncthreads();
  const int nr = t >> 2, ks = (t & 3) * 16;
  unsigned short ov[16];
#pragma unroll
  for (int i = 0; i < 16; i++) ov[i] = f2bf(tile[ks + i][nr]);
  unsigned short* dst = woT + (size_t)(ntile * 64 + nr) * 2688 + kt * 64 + ks;
  *(uint4*)(dst) = *(const uint4*)&ov[0];
  *(uint4*)(dst + 8) = *(const uint4*)&ov[8];
}

// ---------------- proj via MFMA ------------------------------------------------------
__global__ __launch_bounds__(256) void proj_mfma(
    const float* __restrict__ s, const unsigned short* __restrict__ wTall,
    const float* __restrict__ bq, const float* __restrict__ bkv,
    const float* __restrict__ bqp, const float* __restrict__ bkvp,
    unsigned short* __restrict__ qbh, unsigned short* __restrict__ kbh,
    float* __restrict__ vb, float* __restrict__ qpraw, float* __restrict__ kvpraw) {
  const int bx = blockIdx.x, row0 = blockIdx.y * 64;
  const int lane = threadIdx.x & 63, wv = threadIdx.x >> 6;
  const int quad = lane >> 4, m = lane & 15;
  const int n0 = bx * 64;
  const float* srow = s + (size_t)(row0 + wv * 16 + m) * 384;
  f32x4 acc[4];
#pragma unroll
  for (int nt = 0; nt < 4; nt++) acc[nt] = (f32x4){0.f, 0.f, 0.f, 0.f};

#pragma unroll
  for (int ksx = 0; ksx < 12; ksx++) {
    const int c0 = ksx * 32 + quad * 8;
    float4 a0 = *(const float4*)(srow + c0);
    float4 a1 = *(const float4*)(srow + c0 + 4);
    short8 af = pack8(a0, a1);
#pragma unroll
    for (int nt = 0; nt < 4; nt++) {
      short8 bf = *(const short8*)(wTall + (size_t)(n0 + nt * 16 + m) * 384 + c0);
      acc[nt] = __builtin_amdgcn_mfma_f32_16x16x32_bf16(af, bf, acc[nt], 0, 0, 0);
    }
  }

  const int rbase = row0 + wv * 16 + quad * 4;
#pragma unroll
  for (int nt = 0; nt < 4; nt++) {
    const int col = n0 + nt * 16 + m;
    if (n0 < 2048) {
      const float bias = bq[col];
#pragma unroll
      for (int r = 0; r < 4; r++)
        qbh[(size_t)(rbase + r) * 2048 + col] = f2bf(acc[nt][r] + bias);
    } else if (n0 < 6144) {
      const int ckv = col - 2048;
      const float bias = bkv[ckv];
      const int hh = ckv >> 9, c = ckv & 511;
      if (c < 256) {
#pragma unroll
        for (int r = 0; r < 4; r++)
          kbh[(size_t)(rbase + r) * 2048 + hh * 256 + c] = f2bf(acc[nt][r] + bias);
      } else {
#pragma unroll
        for (int r = 0; r < 4; r++)
          vb[(size_t)(rbase + r) * 2048 + hh * 256 + (c - 256)] = acc[nt][r] + bias;
      }
    } else if (n0 < 6336) {
      const int cq = col - 6144;
      const float bias = bqp[cq];
#pragma unroll
      for (int r = 0; r < 4; r++)
        qpraw[(size_t)(rbase + r) * 192 + cq] = acc[nt][r] + bias;
    } else {
      const int ck = col - 6336;
      if (ck < 480) {
        const float bias = bkvp[ck];
#pragma unroll
        for (int r = 0; r < 4; r++)
          kvpraw[(size_t)(rbase + r) * 480 + ck] = acc[nt][r] + bias;
      }
    }
  }
}

// ---------------- rigid transform of point projections ------------------------------
__global__ __launch_bounds__(256) void rigid_pts(
    const float* __restrict__ qpraw, const float* __restrict__ kvpraw,
    const float* __restrict__ rot, const float* __restrict__ trans,
    float* __restrict__ qpts, float* __restrict__ kvpts) {
  int gid = blockIdx.x * 256 + threadIdx.x;
  int n = gid / 224, r = gid % 224;
  const float* R  = rot + n * 9;
  const float* tr = trans + n * 3;
  float px, py, pz; float* dst;
  if (r < 64) {
    const float* src = qpraw + (size_t)n * 192;
    px = src[r]; py = src[64 + r]; pz = src[128 + r];
    dst = qpts + ((size_t)n * 64 + r) * 3;
  } else {
    int p = r - 64;
    const float* src = kvpraw + (size_t)n * 480;
    px = src[p]; py = src[160 + p]; pz = src[320 + p];
    dst = kvpts + ((size_t)n * 160 + p) * 3;
  }
  dst[0] = R[0] * px + R[1] * py + R[2] * pz + tr[0];
  dst[1] = R[3] * px + R[4] * py + R[5] * pz + tr[1];
  dst[2] = R[6] * px + R[7] * py + R[8] * pz + tr[2];
}

// ---------------- pts planes: q/k point hi/lo bf16 planes + squared norms -----------
__global__ __launch_bounds__(256) void pts_planes(
    const float* __restrict__ qpts, const float* __restrict__ kvpts,
    unsigned short* __restrict__ qptH, unsigned short* __restrict__ qptL,
    unsigned short* __restrict__ kptH, unsigned short* __restrict__ kptL,
    float* __restrict__ qp2g, float* __restrict__ kp2g) {
  const int row = blockIdx.x * 256 + threadIdx.x;   // grid (2,8): 512 rows
  const int h = blockIdx.y;
  {
    const float* src = qpts + ((size_t)row * 64 + h * 8) * 3;
    unsigned short hi[32], lo[32]; float s2 = 0.f;
#pragma unroll
    for (int w = 0; w < 24; w++) {
      float x = src[w];
      hi[w] = f2bf(x); lo[w] = f2bf(x - bf2f(hi[w]));
      s2 += x * x;
    }
#pragma unroll
    for (int w = 24; w < 32; w++) { hi[w] = 0; lo[w] = 0; }
    unsigned short* dh = qptH + ((size_t)h * 512 + row) * 32;
    unsigned short* dl = qptL + ((size_t)h * 512 + row) * 32;
#pragma unroll
    for (int g = 0; g < 4; g++) {
      *(uint4*)(dh + g * 8) = *(const uint4*)&hi[g * 8];
      *(uint4*)(dl + g * 8) = *(const uint4*)&lo[g * 8];
    }
    qp2g[h * 512 + row] = s2;
  }
  {
    const float* src = kvpts + ((size_t)row * 160 + h * 20) * 3;
    unsigned short hi[32], lo[32]; float s2 = 0.f;
#pragma unroll
    for (int w = 0; w < 24; w++) {
      float x = src[w];
      hi[w] = f2bf(x); lo[w] = f2bf(x - bf2f(hi[w]));
      s2 += x * x;
    }
#pragma unroll
    for (int w = 24; w < 32; w++) { hi[w] = 0; lo[w] = 0; }
    unsigned short* dh = kptH + ((size_t)h * 512 + row) * 32;
    unsigned short* dl = kptL + ((size_t)h * 512 + row) * 32;
#pragma unroll
    for (int g = 0; g < 4; g++) {
      *(uint4*)(dh + g * 8) = *(const uint4*)&hi[g * 8];
      *(uint4*)(dl + g * 8) = *(const uint4*)&lo[g * 8];
    }
    kp2g[h * 512 + row] = s2;
  }
}

// ---------------- pack z-weights transposed bf16 ------------------------------------
__global__ __launch_bounds__(256) void prep_wT(
    const float* __restrict__ wb, const float* __restrict__ wz,
    unsigned short* __restrict__ wT) {
  int l = blockIdx.x * 256 + threadIdx.x;  // 48*128 = 6144
  if (l < 6144) {
    int n = l >> 7, k = l & 127;
    float v = (n < 8) ? wb[k * 8 + n] * 0.5773502691896258f
                      : (n < 40 ? wz[k * 32 + (n - 8)] : 0.f);
    wT[l] = f2bf(v);
  }
}

// ---------------- z-pass: MFMA + LDS repack -> coalesced bf16 outputs ---------------
__global__ __launch_bounds__(256) void zpass_mfma(
    const float* __restrict__ z, const unsigned short* __restrict__ wT,
    const float* __restrict__ bb, const float* __restrict__ bz,
    unsigned short* __restrict__ bbias_tb, unsigned short* __restrict__ pairzT) {
  __shared__ __align__(16) unsigned short lb[4][8][16];
  __shared__ __align__(16) unsigned short lp[4][32][16];
  const int lane = threadIdx.x & 63;
  const int wave = threadIdx.x >> 6;
  const int quad = lane >> 4, m = lane & 15;
  const int tile = blockIdx.x * 4 + wave;
  const int row0 = tile * 16;

  short8 bf[3][4];
#pragma unroll
  for (int nt = 0; nt < 3; nt++)
#pragma unroll
    for (int s = 0; s < 4; s++)
      bf[nt][s] = *(const short8*)(wT + (size_t)(nt * 16 + m) * 128 + s * 32 + quad * 8);

  float bias[3];
#pragma unroll
  for (int nt = 0; nt < 3; nt++) {
    int c = nt * 16 + m;
    bias[nt] = (c < 8) ? 0.5773502691896258f * bb[c] : (c < 40 ? bz[c - 8] : 0.f);
  }

  f32x4 acc[3];
#pragma unroll
  for (int nt = 0; nt < 3; nt++) acc[nt] = (f32x4){0.f, 0.f, 0.f, 0.f};

  const float* zr = z + (size_t)(row0 + m) * 128 + quad * 8;
#pragma unroll
  for (int s = 0; s < 4; s++) {
    float4 a0 = *(const float4*)(zr + s * 32);
    float4 a1 = *(const float4*)(zr + s * 32 + 4);
    short8 af = pack8(a0, a1);
#pragma unroll
    for (int nt = 0; nt < 3; nt++)
      acc[nt] = __builtin_amdgcn_mfma_f32_16x16x32_bf16(af, bf[nt][s], acc[nt], 0, 0, 0);
  }

#pragma unroll
  for (int nt = 0; nt < 3; nt++) {
    const int c = nt * 16 + m;
#pragma unroll
    for (int r = 0; r < 4; r++) {
      const float v = acc[nt][r] + bias[nt];
      const int jl = quad * 4 + r;
      if (c < 8)       lb[wave][c][jl] = f2bf(v);
      else if (c < 40) lp[wave][c - 8][jl] = f2bf(v);
    }
  }
  const int i = row0 >> 9, j0 = row0 & 511;
  if (lane < 16) {
    int c = lane >> 1, half = lane & 1;
    uint4 val = *(const uint4*)&lb[wave][c][half * 8];
    *(uint4*)(bbias_tb + (size_t)c * 262144 + row0 + half * 8) = val;
  }
  {
    int d = lane >> 1, half = lane & 1;
    uint4 val = *(const uint4*)&lp[wave][d][half * 8];
    *(uint4*)(pairzT + ((size_t)i * 32 + d) * 512 + j0 + half * 8) = val;
  }
}

// ---------------- vptT prep: [h][n][j] bf16, n: 0-255 v, 256-303 ptsHi, 304-351 ptsLo
__global__ __launch_bounds__(256) void vpt_prep(
    const float* __restrict__ vb, const float* __restrict__ kvpts,
    unsigned short* __restrict__ vptT) {
  const int jt = blockIdx.x, h = blockIdx.y, part = blockIdx.z;
  const int j0 = jt * 64, t = threadIdx.x;
  if (part < 4) {
    __shared__ float tile[64][65];
    const int c0 = part * 64;
    const int r = t >> 2, cs = (t & 3) * 16;
#pragma unroll
    for (int ii = 0; ii < 16; ii += 4) {
      float4 v = *(const float4*)(vb + (size_t)(j0 + r) * 2048 + h * 256 + c0 + cs + ii);
      tile[r][cs + ii + 0] = v.x; tile[r][cs + ii + 1] = v.y;
      tile[r][cs + ii + 2] = v.z; tile[r][cs + ii + 3] = v.w;
    }
    __syncthreads();
    const int cl = t >> 2, js = (t & 3) * 16;
    unsigned short ov[16];
#pragma unroll
    for (int x = 0; x < 16; x++) ov[x] = f2bf(tile[js + x][cl]);
    unsigned short* dst = vptT + ((size_t)h * 352 + c0 + cl) * 512 + j0 + js;
    *(uint4*)dst = *(const uint4*)&ov[0];
    *(uint4*)(dst + 8) = *(const uint4*)&ov[8];
  } else {
    __shared__ float lds[64][37];
    for (int l = t; l < 64 * 36; l += 256) {
      int jl = l / 36, w = l % 36;
      lds[jl][w] = kvpts[((size_t)(j0 + jl) * 160 + h * 20 + 8) * 3 + w];
    }
    __syncthreads();
#pragma unroll
    for (int step = 0; step < 3; step++) {
      int chunk = t + 256 * step;          // < 768 = 96 rows x 8 chunks
      int row = chunk >> 3, js = (chunk & 7) * 8;
      unsigned short ov[8];
#pragma unroll
      for (int x = 0; x < 8; x++) {
        int w = (row < 48) ? row : row - 48;
        float f = (w < 36) ? lds[js + x][w] : 0.f;
        unsigned short hi = f2bf(f);
        ov[x] = (row < 48) ? hi : f2bf(f - bf2f(hi));
      }
      *(uint4*)(vptT + ((size_t)h * 352 + 256 + row) * 512 + j0 + js) = *(const uint4*)&ov[0];
    }
  }
}

// ---------------- fused logits + softmax + a@[v,pts] --------------------------------
// grid (32, 8): block = 16 i-rows x 512 j for head h; wave w owns j-slice [w*128, +128)
// phase1: QK + pt MFMAs -> logits -> softmax -> sth/stl LDS (+ attnh global for o_pair)
// phase2: a @ vptT (22 n-tiles split across waves), write featsb o/pts/norm
__global__ __launch_bounds__(256) void logits_fused(
    const unsigned short* __restrict__ qbh, const unsigned short* __restrict__ kbh,
    const unsigned short* __restrict__ qptH, const unsigned short* __restrict__ qptL,
    const unsigned short* __restrict__ kptH, const unsigned short* __restrict__ kptL,
    const float* __restrict__ qp2g, const float* __restrict__ kp2g,
    const unsigned short* __restrict__ bbias_tb, const float* __restrict__ mask,
    const float* __restrict__ hwp, const unsigned short* __restrict__ vptT,
    const float* __restrict__ rot, const float* __restrict__ trans,
    unsigned short* __restrict__ attnh, unsigned short* __restrict__ featsb) {
  const int it = blockIdx.x, h = blockIdx.y;
  const int i0 = it * 16;
  __shared__ __align__(16) unsigned short sth[4][16][136], stl[4][16][136];
  __shared__ float redm[16][4], reds[16][4];
  __shared__ float lds_h[16][48], lds_l[16][48];
  const int t = threadIdx.x;
  const int lane = t & 63, wv = t >> 6;
  const int quad = lane >> 4, m = lane & 15;
  const int jw0 = wv * 128;

  // ---- QK^T ----
  f32x4 acc[8];
#pragma unroll
  for (int nt = 0; nt < 8; nt++) acc[nt] = (f32x4){0.f, 0.f, 0.f, 0.f};
  const unsigned short* qrow = qbh + (size_t)(i0 + m) * 2048 + h * 256;
#pragma unroll
  for (int s = 0; s < 8; s++) {
    short8 af = *(const short8*)(qrow + s * 32 + quad * 8);
#pragma unroll
    for (int nt = 0; nt < 8; nt++) {
      short8 bfr = *(const short8*)(kbh + (size_t)(jw0 + nt * 16 + m) * 2048 + h * 256 + s * 32 + quad * 8);
      acc[nt] = __builtin_amdgcn_mfma_f32_16x16x32_bf16(af, bfr, acc[nt], 0, 0, 0);
    }
  }

  // ---- point cross-term (hi/lo split) from global planes ----
  short8 aqh = *(const short8*)(qptH + ((size_t)h * 512 + i0 + m) * 32 + quad * 8);
  short8 aql = *(const short8*)(qptL + ((size_t)h * 512 + i0 + m) * 32 + quad * 8);
  f32x4 accp[8];
#pragma unroll
  for (int nt = 0; nt < 8; nt++) {
    const size_t krow = ((size_t)h * 512 + jw0 + nt * 16 + m) * 32 + quad * 8;
    short8 bkh = *(const short8*)(kptH + krow);
    short8 bkl = *(const short8*)(kptL + krow);
    f32x4 p = (f32x4){0.f, 0.f, 0.f, 0.f};
    p = __builtin_amdgcn_mfma_f32_16x16x32_bf16(aqh, bkh, p, 0, 0, 0);
    p = __builtin_amdgcn_mfma_f32_16x16x32_bf16(aqh, bkl, p, 0, 0, 0);
    p = __builtin_amdgcn_mfma_f32_16x16x32_bf16(aql, bkh, p, 0, 0, 0);
    accp[nt] = p;
  }

  // ---- logits ----
  const float c1 = 0.03608439182435161f;                         // 1/sqrt(768)
  const float hw = log1pf(expf(hwp[h])) * 0.09622504486493764f;  // softplus*sqrt(1/108)
  float qp2v[4];
#pragma unroll
  for (int r = 0; r < 4; r++) qp2v[r] = qp2g[h * 512 + i0 + quad * 4 + r];
  float lg[8][4];
  float rmax[4] = {-1e30f, -1e30f, -1e30f, -1e30f};
#pragma unroll
  for (int nt = 0; nt < 8; nt++) {
    const int j = jw0 + nt * 16 + m;
    const float kp2v = kp2g[h * 512 + j];
    const float mj = mask[j];
#pragma unroll
    for (int r = 0; r < 4; r++) {
      const int il = quad * 4 + r;
      const float pt = qp2v[r] + kp2v - 2.f * accp[nt][r];
      float v = c1 * acc[nt][r]
              + bf2f(bbias_tb[(size_t)h * 262144 + (size_t)(i0 + il) * 512 + j])
              - 0.5f * hw * pt
              + 100000.f * (mask[i0 + il] * mj - 1.f);
      lg[nt][r] = v;
      rmax[r] = fmaxf(rmax[r], v);
    }
  }
  // ---- softmax (cross-lane then cross-wave) ----
#pragma unroll
  for (int r = 0; r < 4; r++) {
#pragma unroll
    for (int off = 1; off < 16; off <<= 1) rmax[r] = fmaxf(rmax[r], __shfl_xor(rmax[r], off));
  }
  if (m == 0) {
#pragma unroll
    for (int r = 0; r < 4; r++) redm[quad * 4 + r][wv] = rmax[r];
  }
  __syncthreads();
  float rowm[4], rsum[4];
#pragma unroll
  for (int r = 0; r < 4; r++) {
    const int il = quad * 4 + r;
    rowm[r] = fmaxf(fmaxf(redm[il][0], redm[il][1]), fmaxf(redm[il][2], redm[il][3]));
    rsum[r] = 0.f;
  }
#pragma unroll
  for (int nt = 0; nt < 8; nt++)
#pragma unroll
    for (int r = 0; r < 4; r++) {
      float e = __expf(lg[nt][r] - rowm[r]);
      lg[nt][r] = e;
      rsum[r] += e;
    }
#pragma unroll
  for (int r = 0; r < 4; r++) {
#pragma unroll
    for (int off = 1; off < 16; off <<= 1) rsum[r] += __shfl_xor(rsum[r], off);
  }
  if (m == 0) {
#pragma unroll
    for (int r = 0; r < 4; r++) reds[quad * 4 + r][wv] = rsum[r];
  }
  __syncthreads();
  float inv[4];
#pragma unroll
  for (int r = 0; r < 4; r++) {
    const int il = quad * 4 + r;
    inv[r] = 1.f / (reds[il][0] + reds[il][1] + reds[il][2] + reds[il][3]);
  }
  // ---- a -> bf16 hi/lo into LDS ----
#pragma unroll
  for (int nt = 0; nt < 8; nt++)
#pragma unroll
    for (int r = 0; r < 4; r++) {
      const int il = quad * 4 + r;
      float a = lg[nt][r] * inv[r];
      unsigned short hi = f2bf(a);
      sth[wv][il][nt * 16 + m] = hi;
      stl[wv][il][nt * 16 + m] = f2bf(a - bf2f(hi));
    }
  __syncthreads();
  // attnh global (hi only, for o_pair), coalesced
#pragma unroll
  for (int step = 0; step < 4; step++) {
    const int idx = lane + 64 * step;        // 16 rows x 16 segs
    const int il = idx >> 4, seg = idx & 15;
    uint4 vh = *(const uint4*)&sth[wv][il][seg * 8];
    *(uint4*)(attnh + ((size_t)h * 512 + i0 + il) * 512 + jw0 + seg * 8) = vh;
  }

  // ---- phase 2: a @ vptT (A-frags from LDS across all 4 j-slices) ----
  const int nt0 = wv * 6;
  const int ncnt = (wv == 3) ? 4 : 6;
  f32x4 vacc[6];
#pragma unroll
  for (int k = 0; k < 6; k++) vacc[k] = (f32x4){0.f, 0.f, 0.f, 0.f};
  const unsigned short* vbase = vptT + (size_t)h * 352 * 512;
#pragma unroll
  for (int s = 0; s < 16; s++) {
    const int wsrc = s >> 2, col = (s & 3) * 32 + quad * 8;
    short8 ah = *(const short8*)&sth[wsrc][m][col];
    short8 al = *(const short8*)&stl[wsrc][m][col];
    const int ko = s * 32 + quad * 8;
#pragma unroll
    for (int k = 0; k < 6; k++) {
      if (k < ncnt) {
        const int nt = nt0 + k;
        short8 bfr = *(const short8*)(vbase + (size_t)(nt * 16 + m) * 512 + ko);
        vacc[k] = __builtin_amdgcn_mfma_f32_16x16x32_bf16(ah, bfr, vacc[k], 0, 0, 0);
        if (nt >= 16 && nt < 19)
          vacc[k] = __builtin_amdgcn_mfma_f32_16x16x32_bf16(al, bfr, vacc[k], 0, 0, 0);
      }
    }
  }
#pragma unroll
  for (int k = 0; k < 6; k++) {
    if (k < ncnt) {
      const int nt = nt0 + k;
      if (nt < 16) {
#pragma unroll
        for (int r = 0; r < 4; r++)
          featsb[(size_t)(i0 + quad * 4 + r) * 2688 + h * 256 + nt * 16 + m] = f2bf(vacc[k][r]);
      } else if (nt < 19) {
        const int w = (nt - 16) * 16 + m;
#pragma unroll
        for (int r = 0; r < 4; r++) if (w < 36) lds_h[quad * 4 + r][w] = vacc[k][r];
      } else {
        const int w = (nt - 19) * 16 + m;
#pragma unroll
        for (int r = 0; r < 4; r++) if (w < 36) lds_l[quad * 4 + r][w] = vacc[k][r];
      }
    }
  }
  __syncthreads();
  if (t < 192) {
    const int il = t / 12, p = t % 12, irow = i0 + il;
    const float* R = rot + irow * 9;
    const float* tr = trans + irow * 3;
    float x  = lds_h[il][p * 3 + 0] + lds_l[il][p * 3 + 0] - tr[0];
    float y  = lds_h[il][p * 3 + 1] + lds_l[il][p * 3 + 1] - tr[1];
    float zz = lds_h[il][p * 3 + 2] + lds_l[il][p * 3 + 2] - tr[2];
    float o0 = R[0] * x + R[3] * y + R[6] * zz;   // R^T v
    float o1 = R[1] * x + R[4] * y + R[7] * zz;
    float o2 = R[2] * x + R[5] * y + R[8] * zz;
    float nrm = sqrtf(o0 * o0 + o1 * o1 + o2 * o2 + 1e-8f);
    unsigned short* fr = featsb + (size_t)irow * 2688 + 2048;
    fr[h * 12 + p]       = f2bf(o0);
    fr[96 + h * 12 + p]  = f2bf(o1);
    fr[192 + h * 12 + p] = f2bf(o2);
    fr[288 + h * 12 + p] = f2bf(nrm);
  }
}

// ---------------- o_pair via MFMA: per-i [8h x 512j] @ [512j x 32d] ------------------
__global__ __launch_bounds__(256) void o_pair_mfma(
    const unsigned short* __restrict__ attnh, const unsigned short* __restrict__ pairzT,
    unsigned short* __restrict__ featsb) {
  const int lane = threadIdx.x & 63, wv = threadIdx.x >> 6;
  const int quad = lane >> 4, m = lane & 15;
  const int i = blockIdx.x * 4 + wv;          // grid 128
  f32x4 acc[2];
  acc[0] = (f32x4){0.f, 0.f, 0.f, 0.f};
  acc[1] = (f32x4){0.f, 0.f, 0.f, 0.f};
#pragma unroll
  for (int s = 0; s < 16; s++) {
    const int ko = s * 32 + quad * 8;
    short8 af = *(const short8*)(attnh + (size_t)(m & 7) * 262144 + (size_t)i * 512 + ko);
#pragma unroll
    for (int nt = 0; nt < 2; nt++) {
      short8 bfr = *(const short8*)(pairzT + ((size_t)i * 32 + nt * 16 + m) * 512 + ko);
      acc[nt] = __builtin_amdgcn_mfma_f32_16x16x32_bf16(af, bfr, acc[nt], 0, 0, 0);
    }
  }
  if (quad < 2) {
#pragma unroll
    for (int nt = 0; nt < 2; nt++)
#pragma unroll
      for (int r = 0; r < 4; r++) {
        const int hh = quad * 4 + r, d = nt * 16 + m;
        featsb[(size_t)i * 2688 + 2432 + hh * 32 + d] = f2bf(acc[nt][r]);
      }
  }
}

// ---------------- out = featsb @ woT^T + bo via MFMA (no atomics) -------------------
__global__ __launch_bounds__(256) void out_mfma(
    const unsigned short* __restrict__ featsb, const unsigned short* __restrict__ woT,
    const float* __restrict__ bo, float* __restrict__ out) {
  const int it = blockIdx.x, ng = blockIdx.y;   // grid (32, 6)
  const int lane = threadIdx.x & 63, wv = threadIdx.x >> 6;
  const int quad = lane >> 4, m = lane & 15;
  const int i0 = it * 16, n0 = (ng * 4 + wv) * 16;
  const unsigned short* arow = featsb + (size_t)(i0 + m) * 2688;
  const unsigned short* brow = woT + (size_t)(n0 + m) * 2688;
  f32x4 acc = (f32x4){0.f, 0.f, 0.f, 0.f};
#pragma unroll 4
  for (int s = 0; s < 84; s++) {
    const int ko = s * 32 + quad * 8;
    short8 af = *(const short8*)(arow + ko);
    short8 bf = *(const short8*)(brow + ko);
    acc = __builtin_amdgcn_mfma_f32_16x16x32_bf16(af, bf, acc, 0, 0, 0);
  }
  const float bias = bo[n0 + m];
#pragma unroll
  for (int r = 0; r < 4; r++)
    out[(size_t)(i0 + quad * 4 + r) * 384 + n0 + m] = acc[r] + bias;
}

extern "C" void kernel_launch(void* const* d_in, const int* in_sizes, int n_in,
                              void* d_out, int out_size, void* d_ws, size_t ws_size,
                              hipStream_t stream) {
  const float* s     = (const float*)d_in[0];
  const float* z     = (const float*)d_in[1];
  const float* rot   = (const float*)d_in[2];
  const float* trans = (const float*)d_in[3];
  const float* mask  = (const float*)d_in[4];
  const float* wq    = (const float*)d_in[5];
  const float* bq    = (const float*)d_in[6];
  const float* wkv   = (const float*)d_in[7];
  const float* bkv   = (const float*)d_in[8];
  const float* wqp   = (const float*)d_in[9];
  const float* bqp   = (const float*)d_in[10];
  const float* wkvp  = (const float*)d_in[11];
  const float* bkvp  = (const float*)d_in[12];
  const float* wb    = (const float*)d_in[13];
  const float* bb    = (const float*)d_in[14];
  const float* wz    = (const float*)d_in[15];
  const float* bz    = (const float*)d_in[16];
  const float* hwp   = (const float*)d_in[17];
  const float* wo    = (const float*)d_in[18];
  const float* bo    = (const float*)d_in[19];
  float* out = (float*)d_out;

  float* ws = (float*)d_ws;
  unsigned short* qbh   = (unsigned short*)(ws + OFF_QBH);
  unsigned short* kbh   = (unsigned short*)(ws + OFF_KBH);
  float* vb      = ws + OFF_VB;
  float* qpraw   = ws + OFF_QPRAW;
  float* kvpraw  = ws + OFF_KVPRAW;
  float* qpts    = ws + OFF_QPTS;
  float* kvpts   = ws + OFF_KVPTS;
  unsigned short* bbias_tb = (unsigned short*)(ws + OFF_BBIAS);
  unsigned short* pairzT   = (unsigned short*)(ws + OFF_PAIRZT);
  unsigned short* attnh    = (unsigned short*)(ws + OFF_ATTNH);
  unsigned short* featsb   = (unsigned short*)(ws + OFF_FEATSB);
  unsigned short* wT    = (unsigned short*)(ws + OFF_WCAT);
  unsigned short* wTall = (unsigned short*)(ws + OFF_WTALL);
  unsigned short* vptT  = (unsigned short*)(ws + OFF_VPT);
  unsigned short* woT   = (unsigned short*)(ws + OFF_WOT);
  unsigned short* qptH  = (unsigned short*)(ws + OFF_QPTH);
  unsigned short* qptL  = (unsigned short*)(ws + OFF_QPTL);
  unsigned short* kptH  = (unsigned short*)(ws + OFF_KPTH);
  unsigned short* kptL  = (unsigned short*)(ws + OFF_KPTL);
  float* qp2g = ws + OFF_QP2;
  float* kp2g = ws + OFF_KP2;

  prep_wT_all<<<dim3(107, 6), 256, 0, stream>>>(wq, wkv, wqp, wkvp, wTall);
  prep_wT<<<24, 256, 0, stream>>>(wb, wz, wT);
  prep_woT<<<dim3(42, 6), 256, 0, stream>>>(wo, woT);
  proj_mfma<<<dim3(107, 8), 256, 0, stream>>>(s, wTall, bq, bkv, bqp, bkvp,
                                              qbh, kbh, vb, qpraw, kvpraw);
  rigid_pts<<<448, 256, 0, stream>>>(qpraw, kvpraw, rot, trans, qpts, kvpts);
  pts_planes<<<dim3(2, 8), 256, 0, stream>>>(qpts, kvpts, qptH, qptL, kptH, kptL, qp2g, kp2g);
  zpass_mfma<<<4096, 256, 0, stream>>>(z, wT, bb, bz, bbias_tb, pairzT);
  vpt_prep<<<dim3(8, 8, 5), 256, 0, stream>>>(vb, kvpts, vptT);
  logits_fused<<<dim3(32, 8), 256, 0, stream>>>(qbh, kbh, qptH, qptL, kptH, kptL,
                                                qp2g, kp2g, bbias_tb, mask, hwp,
                                                vptT, rot, trans, attnh, featsb);
  o_pair_mfma<<<128, 256, 0, stream>>>(attnh, pairzT, featsb);
  out_mfma<<<dim3(32, 6), 256, 0, stream>>>(featsb, woT, bo, out);
}